// Round 8
// baseline (625.512 us; speedup 1.0000x reference)
//
#include <hip/hip_runtime.h>

#define F 128
#define GSZ 128          // dst nodes per partition
#define GSH 7
#define CAP 1536         // partition capacity; mean E/NPART ~1023, 16-sigma margin

typedef __bf16 bf16x8 __attribute__((ext_vector_type(8)));
typedef unsigned short ushort8 __attribute__((ext_vector_type(8)));
typedef unsigned short ushort4v __attribute__((ext_vector_type(4)));
typedef float f32x4 __attribute__((ext_vector_type(4)));

// fp32 -> bf16 bits with round-to-nearest-even (inputs finite).
static __device__ __forceinline__ unsigned short f2bf(float f) {
    unsigned int u = __float_as_uint(f);
    u += 0x7fffu + ((u >> 16) & 1u);
    return (unsigned short)(u >> 16);
}
// packed uint (2 bf16) -> 2 floats
static __device__ __forceinline__ void bf2x(unsigned int u, float& lo, float& hi) {
    lo = __uint_as_float(u << 16);
    hi = __uint_as_float(u & 0xffff0000u);
}

#define WPITCH 136  // ushorts per WT row: 128 + 8 pad

// Y_bf16[n,128] = act(X[n,128]) @ W[128,128] via bf16 MFMA, fp32 accumulate.
// INBF: X is bf16 (ushort) rows; else fp32. RELU applied to X.
template <int RELU, int INBF>
__global__ __launch_bounds__(256) void gemm128_mfma(const void* __restrict__ Xv,
                                                    const float* __restrict__ W,
                                                    unsigned short* __restrict__ Y,
                                                    int n) {
    __shared__ __align__(16) unsigned short WT[F * WPITCH];  // WT[col][k], bf16 bits
    for (int idx = threadIdx.x; idx < F * F; idx += 256) {
        const int k = idx >> 7, c = idx & 127;
        WT[c * WPITCH + k] = f2bf(W[idx]);
    }
    __syncthreads();

    const int lane = threadIdx.x & 63;
    const int wv = threadIdx.x >> 6;
    const int m15 = lane & 15;
    const int quad = lane >> 4;
    const int rowBase = blockIdx.x * 128 + wv * 32;

    f32x4 acc[2][8];
#pragma unroll
    for (int rt = 0; rt < 2; ++rt)
#pragma unroll
        for (int ct = 0; ct < 8; ++ct) acc[rt][ct] = (f32x4){0.f, 0.f, 0.f, 0.f};

    int rA[2];
    rA[0] = min(rowBase + m15, n - 1);        // clamped; stores masked below
    rA[1] = min(rowBase + 16 + m15, n - 1);

#pragma unroll
    for (int ks = 0; ks < 4; ++ks) {
        const int k0 = ks * 32 + quad * 8;    // this lane's 8-wide k window
        bf16x8 a[2];
#pragma unroll
        for (int rt = 0; rt < 2; ++rt) {
            if (INBF) {
                const unsigned short* Xb = (const unsigned short*)Xv;
                ushort8 u = *(const ushort8*)(Xb + (size_t)rA[rt] * F + k0);
                if (RELU) {
#pragma unroll
                    for (int j = 0; j < 8; ++j) u[j] = (u[j] & 0x8000u) ? 0 : u[j];
                }
                a[rt] = __builtin_bit_cast(bf16x8, u);
            } else {
                const float* Xf = (const float*)Xv;
                const float* p = Xf + (size_t)rA[rt] * F + k0;
                float4 lo = *(const float4*)p;
                float4 hi = *(const float4*)(p + 4);
                if (RELU) {
                    lo.x = fmaxf(lo.x, 0.f); lo.y = fmaxf(lo.y, 0.f);
                    lo.z = fmaxf(lo.z, 0.f); lo.w = fmaxf(lo.w, 0.f);
                    hi.x = fmaxf(hi.x, 0.f); hi.y = fmaxf(hi.y, 0.f);
                    hi.z = fmaxf(hi.z, 0.f); hi.w = fmaxf(hi.w, 0.f);
                }
                ushort8 u;
                u[0] = f2bf(lo.x); u[1] = f2bf(lo.y); u[2] = f2bf(lo.z); u[3] = f2bf(lo.w);
                u[4] = f2bf(hi.x); u[5] = f2bf(hi.y); u[6] = f2bf(hi.z); u[7] = f2bf(hi.w);
                a[rt] = __builtin_bit_cast(bf16x8, u);
            }
        }
#pragma unroll
        for (int ct = 0; ct < 8; ++ct) {
            const int nn = ct * 16 + m15;
            const bf16x8 b = *(const bf16x8*)(WT + nn * WPITCH + k0);  // ds_read_b128
            acc[0][ct] = __builtin_amdgcn_mfma_f32_16x16x32_bf16(a[0], b, acc[0][ct], 0, 0, 0);
            acc[1][ct] = __builtin_amdgcn_mfma_f32_16x16x32_bf16(a[1], b, acc[1][ct], 0, 0, 0);
        }
    }

    // C/D layout: col = lane&15, row = quad*4 + reg (within each 16x16 tile)
#pragma unroll
    for (int rt = 0; rt < 2; ++rt)
#pragma unroll
        for (int reg = 0; reg < 4; ++reg) {
            const int row = rowBase + rt * 16 + quad * 4 + reg;
            if (row < n) {
#pragma unroll
                for (int ct = 0; ct < 8; ++ct)
                    Y[(size_t)row * F + ct * 16 + m15] = f2bf(acc[rt][ct][reg]);
            }
        }
}

// --- two-pass partition sort of edges by destination -------------------------

// Pass 1: scatter edge e to partition dst>>GSH (appended via hot per-partition
// cursor). Payload packs (src | dstLocal<<24, w-bits) into 8 B.
__global__ __launch_bounds__(256) void pfill(const int* __restrict__ ei,
                                             const float* __restrict__ ew,
                                             int* __restrict__ pcur,
                                             uint2* __restrict__ Epart, int E) {
    const int e = blockIdx.x * 256 + threadIdx.x;
    if (e >= E) return;
    const unsigned int dst = (unsigned int)ei[E + e];
    const unsigned int src = (unsigned int)ei[e];
    const int p = (int)(dst >> GSH);
    const int slot = atomicAdd(&pcur[p], 1);
    if (slot < CAP)   // statistically impossible overflow; guard for memory safety
        Epart[(size_t)p * CAP + slot] =
            make_uint2(src | ((dst & (GSZ - 1)) << 24), (unsigned)__float_as_int(ew[e]));
}

// Pass 2: one block per partition. Stage edges in LDS, histogram+scan the 128
// local dsts, LDS-scatter to dst-sorted order, coalesced write-out. Emits
// ebounds[v] = (beg, end) into the padded Sedge index space.
__global__ __launch_bounds__(256) void sort_fine(const uint2* __restrict__ Epart,
                                                 const int* __restrict__ pcnt,
                                                 uint2* __restrict__ Sedge,
                                                 int2* __restrict__ ebounds, int n) {
    __shared__ uint2 stage[CAP];
    __shared__ uint2 sorted[CAP];
    __shared__ int hist[GSZ], pref[GSZ], cur[GSZ];
    const int p = blockIdx.x;
    const int tid = threadIdx.x;
    const int base = p * CAP;
    int cnt = pcnt[p]; if (cnt > CAP) cnt = CAP;

    if (tid < GSZ) hist[tid] = 0;
    __syncthreads();
    for (int i = tid; i < cnt; i += 256) {
        uint2 e = Epart[(size_t)base + i];
        stage[i] = e;
        atomicAdd(&hist[e.x >> 24], 1);
    }
    __syncthreads();
    if (tid < GSZ) pref[tid] = hist[tid];
    __syncthreads();
    for (int off = 1; off < GSZ; off <<= 1) {
        int t = (tid < GSZ && tid >= off) ? pref[tid - off] : 0;
        __syncthreads();
        if (tid < GSZ) pref[tid] += t;
        __syncthreads();
    }
    if (tid < GSZ) {
        const int inc = pref[tid];
        const int ex = inc - hist[tid];
        cur[tid] = ex;
        const int v = p * GSZ + tid;
        if (v < n) ebounds[v] = make_int2(base + ex, base + inc);
    }
    __syncthreads();
    for (int i = tid; i < cnt; i += 256) {
        uint2 e = stage[i];
        const int pos = atomicAdd(&cur[e.x >> 24], 1);
        sorted[pos] = make_uint2(e.x & 0xFFFFFFu, e.y);
    }
    __syncthreads();
    for (int i = tid; i < cnt; i += 256) Sedge[(size_t)base + i] = sorted[i];
}

// OUT[v] = sum over incoming edges w_e * XW_bf16[src_e]; 32 lanes per node.
// FUSE_U == 1: project fp32 row onto Wlin, write U[v] instead of the row.
template <int FUSE_U>
__global__ __launch_bounds__(256) void gather_agg(const unsigned short* __restrict__ XW,
                                                  const int2* __restrict__ ebounds,
                                                  const uint2* __restrict__ Sedge,
                                                  const float* __restrict__ Wlin,
                                                  unsigned short* __restrict__ OUT,
                                                  float4* __restrict__ U, int n) {
    __shared__ float WL[512];
    if (FUSE_U) {
        for (int i = threadIdx.x; i < 512; i += 256) WL[i] = Wlin[i];
        __syncthreads();
    }
    const int l = threadIdx.x & 31;
    const int v = blockIdx.x * 8 + (threadIdx.x >> 5);
    if (v >= n) return;
    float4 acc = make_float4(0.f, 0.f, 0.f, 0.f);
    const int2 be = ebounds[v];
    int p = be.x;
    const int e2 = be.y;
    for (; p + 4 <= e2; p += 4) {
        const uint2 s0 = Sedge[p],     s1 = Sedge[p + 1];
        const uint2 s2 = Sedge[p + 2], s3 = Sedge[p + 3];
        const uint2 x0 = ((const uint2*)(XW + (size_t)s0.x * F))[l];
        const uint2 x1 = ((const uint2*)(XW + (size_t)s1.x * F))[l];
        const uint2 x2 = ((const uint2*)(XW + (size_t)s2.x * F))[l];
        const uint2 x3 = ((const uint2*)(XW + (size_t)s3.x * F))[l];
        const float w0 = __int_as_float(s0.y), w1 = __int_as_float(s1.y);
        const float w2 = __int_as_float(s2.y), w3 = __int_as_float(s3.y);
        float a0, a1, a2, a3;
        bf2x(x0.x, a0, a1); bf2x(x0.y, a2, a3);
        acc.x = fmaf(w0, a0, acc.x); acc.y = fmaf(w0, a1, acc.y);
        acc.z = fmaf(w0, a2, acc.z); acc.w = fmaf(w0, a3, acc.w);
        bf2x(x1.x, a0, a1); bf2x(x1.y, a2, a3);
        acc.x = fmaf(w1, a0, acc.x); acc.y = fmaf(w1, a1, acc.y);
        acc.z = fmaf(w1, a2, acc.z); acc.w = fmaf(w1, a3, acc.w);
        bf2x(x2.x, a0, a1); bf2x(x2.y, a2, a3);
        acc.x = fmaf(w2, a0, acc.x); acc.y = fmaf(w2, a1, acc.y);
        acc.z = fmaf(w2, a2, acc.z); acc.w = fmaf(w2, a3, acc.w);
        bf2x(x3.x, a0, a1); bf2x(x3.y, a2, a3);
        acc.x = fmaf(w3, a0, acc.x); acc.y = fmaf(w3, a1, acc.y);
        acc.z = fmaf(w3, a2, acc.z); acc.w = fmaf(w3, a3, acc.w);
    }
    for (; p < e2; ++p) {
        const uint2 s = Sedge[p];
        const float w = __int_as_float(s.y);
        const uint2 x = ((const uint2*)(XW + (size_t)s.x * F))[l];
        float a0, a1, a2, a3;
        bf2x(x.x, a0, a1); bf2x(x.y, a2, a3);
        acc.x = fmaf(w, a0, acc.x); acc.y = fmaf(w, a1, acc.y);
        acc.z = fmaf(w, a2, acc.z); acc.w = fmaf(w, a3, acc.w);
    }
    if (!FUSE_U) {
        ushort4v o;
        o[0] = f2bf(acc.x); o[1] = f2bf(acc.y); o[2] = f2bf(acc.z); o[3] = f2bf(acc.w);
        *(ushort4v*)(OUT + (size_t)v * F + (size_t)l * 4) = o;
    } else {
        const int k = l * 4;
        float s0 = acc.x * WL[k]       + acc.y * WL[k + 1]
                 + acc.z * WL[k + 2]   + acc.w * WL[k + 3];
        float s1 = acc.x * WL[128 + k] + acc.y * WL[128 + k + 1]
                 + acc.z * WL[128 + k + 2] + acc.w * WL[128 + k + 3];
        float s2 = acc.x * WL[256 + k] + acc.y * WL[256 + k + 1]
                 + acc.z * WL[256 + k + 2] + acc.w * WL[256 + k + 3];
        float s3 = acc.x * WL[384 + k] + acc.y * WL[384 + k + 1]
                 + acc.z * WL[384 + k + 2] + acc.w * WL[384 + k + 3];
#pragma unroll
        for (int off = 16; off > 0; off >>= 1) {
            s0 += __shfl_down(s0, off, 32);
            s1 += __shfl_down(s1, off, 32);
            s2 += __shfl_down(s2, off, 32);
            s3 += __shfl_down(s3, off, 32);
        }
        if (l == 0) U[v] = make_float4(s0, s1, s2, s3);
    }
}

// out[p,:] = (U[a].x + U[b].y, U[a].z + U[b].w); one thread per pair.
__global__ __launch_bounds__(256) void pair_combine(const float4* __restrict__ U,
                                                    const int* __restrict__ pos,
                                                    float* __restrict__ out, int P) {
    const int p = blockIdx.x * 256 + threadIdx.x;
    if (p >= P) return;
    const int a = pos[p];
    const int b = pos[P + p];
    const float4 ua = U[a];
    const float4 ub = U[b];
    *(float2*)(out + (size_t)p * 2) = make_float2(ua.x + ub.y, ua.z + ub.w);
}

extern "C" void kernel_launch(void* const* d_in, const int* in_sizes, int n_in,
                              void* d_out, int out_size, void* d_ws, size_t ws_size,
                              hipStream_t stream) {
    const float* x    = (const float*)d_in[0];
    const int*   ei1  = (const int*)  d_in[1];
    const int*   ei2  = (const int*)  d_in[2];
    const float* ew1  = (const float*)d_in[3];
    const float* ew2  = (const float*)d_in[4];
    const int*   pos  = (const int*)  d_in[5];
    const float* W1   = (const float*)d_in[6];
    const float* W2   = (const float*)d_in[7];
    const float* Wlin = (const float*)d_in[8];
    float* out = (float*)d_out;

    const int N  = in_sizes[0] / F;
    const int E1 = in_sizes[1] / 2;
    const int E2 = in_sizes[2] / 2;
    const int P  = in_sizes[5] / 2;
    const int NPART = (N + GSZ - 1) >> GSH;        // 782 for N=100k

    // workspace layout
    unsigned short* Abf = (unsigned short*)d_ws;   // N x 128 bf16 (GEMM out)
    unsigned short* Bbf = Abf + (size_t)N * F;     // N x 128 bf16 (gather-1 out)
    uintptr_t up  = (uintptr_t)(Bbf + (size_t)N * F);
    up = (up + 15) & ~(uintptr_t)15;
    float4* U       = (float4*)up;                 // N (node projections)
    int2*   ebounds = (int2*)(U + N);              // N
    int*    pcur    = (int*)(ebounds + N);         // NPART
    uintptr_t sp  = (uintptr_t)(pcur + NPART);
    sp = (sp + 15) & ~(uintptr_t)15;
    uint2* Epart  = (uint2*)sp;                    // NPART*CAP (partitioned edges)
    uint2* Sedge  = Epart + (size_t)NPART * CAP;   // NPART*CAP (dst-sorted edges)

    // ---- layer 1: Abf = x @ W1 ; Bbf = segment_sum over edges1 ----
    gemm128_mfma<0, 0><<<(N + 127) / 128, 256, 0, stream>>>(x, W1, Abf, N);

    hipMemsetAsync(pcur, 0, (size_t)NPART * sizeof(int), stream);
    pfill<<<(E1 + 255) / 256, 256, 0, stream>>>(ei1, ew1, pcur, Epart, E1);
    sort_fine<<<NPART, 256, 0, stream>>>(Epart, pcur, Sedge, ebounds, N);
    gather_agg<0><<<(N + 7) / 8, 256, 0, stream>>>(Abf, ebounds, Sedge, Wlin, Bbf, U, N);

    // ---- layer 2: Abf = relu(Bbf) @ W2 ; U = Wlin-projected segment_sum over edges2 ----
    gemm128_mfma<1, 1><<<(N + 127) / 128, 256, 0, stream>>>(Bbf, W2, Abf, N);

    hipMemsetAsync(pcur, 0, (size_t)NPART * sizeof(int), stream);
    pfill<<<(E2 + 255) / 256, 256, 0, stream>>>(ei2, ew2, pcur, Epart, E2);
    sort_fine<<<NPART, 256, 0, stream>>>(Epart, pcur, Sedge, ebounds, N);
    gather_agg<1><<<(N + 7) / 8, 256, 0, stream>>>(Abf, ebounds, Sedge, Wlin, Bbf, U, N);

    // ---- head: out[p] = (U[a].x + U[b].y, U[a].z + U[b].w) ----
    pair_combine<<<(P + 255) / 256, 256, 0, stream>>>(U, pos, out, P);
}

// Round 9
// 305.700 us; speedup vs baseline: 2.0462x; 2.0462x over previous
//
#include <hip/hip_runtime.h>

#define F 128
#define BSH 9            // 512 dst nodes per bin
#define BSZ 512
#define NBLKA 256        // pass-A blocks (each owns a contiguous edge chunk)

typedef __bf16 bf16x8 __attribute__((ext_vector_type(8)));
typedef unsigned short ushort8 __attribute__((ext_vector_type(8)));
typedef unsigned short ushort4v __attribute__((ext_vector_type(4)));
typedef float f32x4 __attribute__((ext_vector_type(4)));

// fp32 -> bf16 bits with round-to-nearest-even (inputs finite).
static __device__ __forceinline__ unsigned short f2bf(float f) {
    unsigned int u = __float_as_uint(f);
    u += 0x7fffu + ((u >> 16) & 1u);
    return (unsigned short)(u >> 16);
}
// packed uint (2 bf16) -> 2 floats
static __device__ __forceinline__ void bf2x(unsigned int u, float& lo, float& hi) {
    lo = __uint_as_float(u << 16);
    hi = __uint_as_float(u & 0xffff0000u);
}

#define WPITCH 136  // ushorts per WT row: 128 + 8 pad

// Y_bf16[n,128] = act(X[n,128]) @ W[128,128] via bf16 MFMA, fp32 accumulate.
template <int RELU, int INBF>
__global__ __launch_bounds__(256) void gemm128_mfma(const void* __restrict__ Xv,
                                                    const float* __restrict__ W,
                                                    unsigned short* __restrict__ Y,
                                                    int n) {
    __shared__ __align__(16) unsigned short WT[F * WPITCH];  // WT[col][k], bf16 bits
    for (int idx = threadIdx.x; idx < F * F; idx += 256) {
        const int k = idx >> 7, c = idx & 127;
        WT[c * WPITCH + k] = f2bf(W[idx]);
    }
    __syncthreads();

    const int lane = threadIdx.x & 63;
    const int wv = threadIdx.x >> 6;
    const int m15 = lane & 15;
    const int quad = lane >> 4;
    const int rowBase = blockIdx.x * 128 + wv * 32;

    f32x4 acc[2][8];
#pragma unroll
    for (int rt = 0; rt < 2; ++rt)
#pragma unroll
        for (int ct = 0; ct < 8; ++ct) acc[rt][ct] = (f32x4){0.f, 0.f, 0.f, 0.f};

    int rA[2];
    rA[0] = min(rowBase + m15, n - 1);        // clamped; stores masked below
    rA[1] = min(rowBase + 16 + m15, n - 1);

#pragma unroll
    for (int ks = 0; ks < 4; ++ks) {
        const int k0 = ks * 32 + quad * 8;    // this lane's 8-wide k window
        bf16x8 a[2];
#pragma unroll
        for (int rt = 0; rt < 2; ++rt) {
            if (INBF) {
                const unsigned short* Xb = (const unsigned short*)Xv;
                ushort8 u = *(const ushort8*)(Xb + (size_t)rA[rt] * F + k0);
                if (RELU) {
#pragma unroll
                    for (int j = 0; j < 8; ++j) u[j] = (u[j] & 0x8000u) ? 0 : u[j];
                }
                a[rt] = __builtin_bit_cast(bf16x8, u);
            } else {
                const float* Xf = (const float*)Xv;
                const float* p = Xf + (size_t)rA[rt] * F + k0;
                float4 lo = *(const float4*)p;
                float4 hi = *(const float4*)(p + 4);
                if (RELU) {
                    lo.x = fmaxf(lo.x, 0.f); lo.y = fmaxf(lo.y, 0.f);
                    lo.z = fmaxf(lo.z, 0.f); lo.w = fmaxf(lo.w, 0.f);
                    hi.x = fmaxf(hi.x, 0.f); hi.y = fmaxf(hi.y, 0.f);
                    hi.z = fmaxf(hi.z, 0.f); hi.w = fmaxf(hi.w, 0.f);
                }
                ushort8 u;
                u[0] = f2bf(lo.x); u[1] = f2bf(lo.y); u[2] = f2bf(lo.z); u[3] = f2bf(lo.w);
                u[4] = f2bf(hi.x); u[5] = f2bf(hi.y); u[6] = f2bf(hi.z); u[7] = f2bf(hi.w);
                a[rt] = __builtin_bit_cast(bf16x8, u);
            }
        }
#pragma unroll
        for (int ct = 0; ct < 8; ++ct) {
            const int nn = ct * 16 + m15;
            const bf16x8 b = *(const bf16x8*)(WT + nn * WPITCH + k0);  // ds_read_b128
            acc[0][ct] = __builtin_amdgcn_mfma_f32_16x16x32_bf16(a[0], b, acc[0][ct], 0, 0, 0);
            acc[1][ct] = __builtin_amdgcn_mfma_f32_16x16x32_bf16(a[1], b, acc[1][ct], 0, 0, 0);
        }
    }

    // C/D layout: col = lane&15, row = quad*4 + reg (within each 16x16 tile)
#pragma unroll
    for (int rt = 0; rt < 2; ++rt)
#pragma unroll
        for (int reg = 0; reg < 4; ++reg) {
            const int row = rowBase + rt * 16 + quad * 4 + reg;
            if (row < n) {
#pragma unroll
                for (int ct = 0; ct < 8; ++ct)
                    Y[(size_t)row * F + ct * 16 + m15] = f2bf(acc[rt][ct][reg]);
            }
        }
}

// --- block-rank radix partition sort of edges by destination -----------------

// Pass A1: per-block LDS histogram over bins (dst>>BSH) -> gh[bin*NBLKA + blk].
__global__ __launch_bounds__(256) void binhist(const int* __restrict__ ei,
                                               int* __restrict__ gh, int E, int nbin) {
    __shared__ int h[1024];
    for (int i = threadIdx.x; i < nbin; i += 256) h[i] = 0;
    __syncthreads();
    const int chunk = (E + NBLKA - 1) / NBLKA;
    const int lo = blockIdx.x * chunk;
    const int hi = min(lo + chunk, E);
    for (int e = lo + threadIdx.x; e < hi; e += 256)
        atomicAdd(&h[((unsigned)ei[E + e]) >> BSH], 1);
    __syncthreads();
    for (int i = threadIdx.x; i < nbin; i += 256) gh[i * NBLKA + blockIdx.x] = h[i];
}

// 3-stage exact scan (from R6) over the (bin,blk) cells.
__global__ __launch_bounds__(256) void scan_pass1(const int* __restrict__ counts,
                                                  int* __restrict__ bsum, int n) {
    __shared__ int sh[256];
    const int base = blockIdx.x * 1024 + threadIdx.x * 4;
    int s = 0;
#pragma unroll
    for (int j = 0; j < 4; ++j) {
        const int i = base + j;
        if (i < n) s += counts[i];
    }
    sh[threadIdx.x] = s;
    __syncthreads();
    for (int off = 128; off > 0; off >>= 1) {
        if (threadIdx.x < off) sh[threadIdx.x] += sh[threadIdx.x + off];
        __syncthreads();
    }
    if (threadIdx.x == 0) bsum[blockIdx.x] = sh[0];
}

__global__ __launch_bounds__(256) void scan_pass2(int* __restrict__ bsum, int nb) {
    __shared__ int sh[256];
    int v = (threadIdx.x < nb) ? bsum[threadIdx.x] : 0;
    sh[threadIdx.x] = v;
    __syncthreads();
    for (int off = 1; off < 256; off <<= 1) {
        int t = (threadIdx.x >= off) ? sh[threadIdx.x - off] : 0;
        __syncthreads();
        sh[threadIdx.x] += t;
        __syncthreads();
    }
    if (threadIdx.x < nb) bsum[threadIdx.x] = sh[threadIdx.x] - v;  // exclusive
    if (threadIdx.x == nb) bsum[nb] = sh[nb - 1];                   // total
}

__global__ __launch_bounds__(256) void scan_pass3(const int* __restrict__ counts,
                                                  const int* __restrict__ bsum,
                                                  int* __restrict__ offs,
                                                  int n, int nb) {
    __shared__ int sh[256];
    const int base = blockIdx.x * 1024 + threadIdx.x * 4;
    int c[4];
    int s = 0;
#pragma unroll
    for (int j = 0; j < 4; ++j) {
        const int i = base + j;
        c[j] = (i < n) ? counts[i] : 0;
        s += c[j];
    }
    int inc = s;
    sh[threadIdx.x] = inc;
    __syncthreads();
    for (int off = 1; off < 256; off <<= 1) {
        int t = (threadIdx.x >= off) ? sh[threadIdx.x - off] : 0;
        __syncthreads();
        sh[threadIdx.x] += t;
        __syncthreads();
    }
    int run = bsum[blockIdx.x] + sh[threadIdx.x] - inc;
#pragma unroll
    for (int j = 0; j < 4; ++j) {
        const int i = base + j;
        if (i < n) offs[i] = run;
        run += c[j];
    }
    if (blockIdx.x == 0 && threadIdx.x == 0) offs[n] = bsum[nb];
}

// Pass A3: re-read chunk, append each edge into this block's reserved run for
// its bin (contiguous ~16-edge runs -> full-line writes, no global atomics).
// Payload: (src | dstLocal<<20, w-bits). src < 2^20, dstLocal < 512.
__global__ __launch_bounds__(256) void binscatter(const int* __restrict__ ei,
                                                  const float* __restrict__ ew,
                                                  const int* __restrict__ ghoffs,
                                                  uint2* __restrict__ Epart,
                                                  int E, int nbin) {
    __shared__ int gbase[1024];
    __shared__ int cur[1024];
    for (int i = threadIdx.x; i < nbin; i += 256) {
        gbase[i] = ghoffs[i * NBLKA + blockIdx.x];
        cur[i] = 0;
    }
    __syncthreads();
    const int chunk = (E + NBLKA - 1) / NBLKA;
    const int lo = blockIdx.x * chunk;
    const int hi = min(lo + chunk, E);
    for (int e = lo + threadIdx.x; e < hi; e += 256) {
        const unsigned int dst = (unsigned int)ei[E + e];
        const unsigned int src = (unsigned int)ei[e];
        const int b = (int)(dst >> BSH);
        const int r = atomicAdd(&cur[b], 1);
        Epart[(size_t)gbase[b] + r] =
            make_uint2(src | ((dst & (BSZ - 1)) << 20), (unsigned)__float_as_int(ew[e]));
    }
}

// Pass B: one block per bin; LDS hist/scan/rank over 512 local dsts; scatter
// within the bin's own span (single-block locality); emit ebounds.
__global__ __launch_bounds__(512) void sort_bin(const uint2* __restrict__ Epart,
                                                const int* __restrict__ ghoffs,
                                                uint2* __restrict__ Sedge,
                                                int2* __restrict__ ebounds,
                                                int n, int nbin) {
    __shared__ int hist[BSZ], pref[BSZ], cur[BSZ];
    const int bin = blockIdx.x;
    const int tid = threadIdx.x;
    const int base = ghoffs[bin * NBLKA];
    const int end  = ghoffs[(bin + 1) * NBLKA];  // bin==nbin-1 hits the sentinel
    hist[tid] = 0;
    __syncthreads();
    for (int i = base + tid; i < end; i += 512)
        atomicAdd(&hist[Epart[i].x >> 20], 1);
    __syncthreads();
    pref[tid] = hist[tid];
    __syncthreads();
    for (int off = 1; off < BSZ; off <<= 1) {
        int t = (tid >= off) ? pref[tid - off] : 0;
        __syncthreads();
        pref[tid] += t;
        __syncthreads();
    }
    {
        const int inc = pref[tid];
        const int ex = inc - hist[tid];
        cur[tid] = ex;
        const int v = (bin << BSH) + tid;
        if (v < n) ebounds[v] = make_int2(base + ex, base + inc);
    }
    __syncthreads();
    for (int i = base + tid; i < end; i += 512) {
        const uint2 e = Epart[i];
        const int pos = atomicAdd(&cur[e.x >> 20], 1);
        Sedge[(size_t)base + pos] = make_uint2(e.x & 0xFFFFFu, e.y);
    }
}

// OUT[v] = sum over incoming edges w_e * XW_bf16[src_e]; 32 lanes per node.
// FUSE_U == 1: project fp32 row onto Wlin, write U[v] instead of the row.
template <int FUSE_U>
__global__ __launch_bounds__(256) void gather_agg(const unsigned short* __restrict__ XW,
                                                  const int2* __restrict__ ebounds,
                                                  const uint2* __restrict__ Sedge,
                                                  const float* __restrict__ Wlin,
                                                  unsigned short* __restrict__ OUT,
                                                  float4* __restrict__ U, int n) {
    __shared__ float WL[512];
    if (FUSE_U) {
        for (int i = threadIdx.x; i < 512; i += 256) WL[i] = Wlin[i];
        __syncthreads();
    }
    const int l = threadIdx.x & 31;
    const int v = blockIdx.x * 8 + (threadIdx.x >> 5);
    if (v >= n) return;
    float4 acc = make_float4(0.f, 0.f, 0.f, 0.f);
    const int2 be = ebounds[v];
    int p = be.x;
    const int e2 = be.y;
    for (; p + 4 <= e2; p += 4) {
        const uint2 s0 = Sedge[p],     s1 = Sedge[p + 1];
        const uint2 s2 = Sedge[p + 2], s3 = Sedge[p + 3];
        const uint2 x0 = ((const uint2*)(XW + (size_t)s0.x * F))[l];
        const uint2 x1 = ((const uint2*)(XW + (size_t)s1.x * F))[l];
        const uint2 x2 = ((const uint2*)(XW + (size_t)s2.x * F))[l];
        const uint2 x3 = ((const uint2*)(XW + (size_t)s3.x * F))[l];
        const float w0 = __int_as_float(s0.y), w1 = __int_as_float(s1.y);
        const float w2 = __int_as_float(s2.y), w3 = __int_as_float(s3.y);
        float a0, a1, a2, a3;
        bf2x(x0.x, a0, a1); bf2x(x0.y, a2, a3);
        acc.x = fmaf(w0, a0, acc.x); acc.y = fmaf(w0, a1, acc.y);
        acc.z = fmaf(w0, a2, acc.z); acc.w = fmaf(w0, a3, acc.w);
        bf2x(x1.x, a0, a1); bf2x(x1.y, a2, a3);
        acc.x = fmaf(w1, a0, acc.x); acc.y = fmaf(w1, a1, acc.y);
        acc.z = fmaf(w1, a2, acc.z); acc.w = fmaf(w1, a3, acc.w);
        bf2x(x2.x, a0, a1); bf2x(x2.y, a2, a3);
        acc.x = fmaf(w2, a0, acc.x); acc.y = fmaf(w2, a1, acc.y);
        acc.z = fmaf(w2, a2, acc.z); acc.w = fmaf(w2, a3, acc.w);
        bf2x(x3.x, a0, a1); bf2x(x3.y, a2, a3);
        acc.x = fmaf(w3, a0, acc.x); acc.y = fmaf(w3, a1, acc.y);
        acc.z = fmaf(w3, a2, acc.z); acc.w = fmaf(w3, a3, acc.w);
    }
    for (; p < e2; ++p) {
        const uint2 s = Sedge[p];
        const float w = __int_as_float(s.y);
        const uint2 x = ((const uint2*)(XW + (size_t)s.x * F))[l];
        float a0, a1, a2, a3;
        bf2x(x.x, a0, a1); bf2x(x.y, a2, a3);
        acc.x = fmaf(w, a0, acc.x); acc.y = fmaf(w, a1, acc.y);
        acc.z = fmaf(w, a2, acc.z); acc.w = fmaf(w, a3, acc.w);
    }
    if (!FUSE_U) {
        ushort4v o;
        o[0] = f2bf(acc.x); o[1] = f2bf(acc.y); o[2] = f2bf(acc.z); o[3] = f2bf(acc.w);
        *(ushort4v*)(OUT + (size_t)v * F + (size_t)l * 4) = o;
    } else {
        const int k = l * 4;
        float s0 = acc.x * WL[k]       + acc.y * WL[k + 1]
                 + acc.z * WL[k + 2]   + acc.w * WL[k + 3];
        float s1 = acc.x * WL[128 + k] + acc.y * WL[128 + k + 1]
                 + acc.z * WL[128 + k + 2] + acc.w * WL[128 + k + 3];
        float s2 = acc.x * WL[256 + k] + acc.y * WL[256 + k + 1]
                 + acc.z * WL[256 + k + 2] + acc.w * WL[256 + k + 3];
        float s3 = acc.x * WL[384 + k] + acc.y * WL[384 + k + 1]
                 + acc.z * WL[384 + k + 2] + acc.w * WL[384 + k + 3];
#pragma unroll
        for (int off = 16; off > 0; off >>= 1) {
            s0 += __shfl_down(s0, off, 32);
            s1 += __shfl_down(s1, off, 32);
            s2 += __shfl_down(s2, off, 32);
            s3 += __shfl_down(s3, off, 32);
        }
        if (l == 0) U[v] = make_float4(s0, s1, s2, s3);
    }
}

// out[p,:] = (U[a].x + U[b].y, U[a].z + U[b].w); one thread per pair.
__global__ __launch_bounds__(256) void pair_combine(const float4* __restrict__ U,
                                                    const int* __restrict__ pos,
                                                    float* __restrict__ out, int P) {
    const int p = blockIdx.x * 256 + threadIdx.x;
    if (p >= P) return;
    const int a = pos[p];
    const int b = pos[P + p];
    const float4 ua = U[a];
    const float4 ub = U[b];
    *(float2*)(out + (size_t)p * 2) = make_float2(ua.x + ub.y, ua.z + ub.w);
}

extern "C" void kernel_launch(void* const* d_in, const int* in_sizes, int n_in,
                              void* d_out, int out_size, void* d_ws, size_t ws_size,
                              hipStream_t stream) {
    const float* x    = (const float*)d_in[0];
    const int*   ei1  = (const int*)  d_in[1];
    const int*   ei2  = (const int*)  d_in[2];
    const float* ew1  = (const float*)d_in[3];
    const float* ew2  = (const float*)d_in[4];
    const int*   pos  = (const int*)  d_in[5];
    const float* W1   = (const float*)d_in[6];
    const float* W2   = (const float*)d_in[7];
    const float* Wlin = (const float*)d_in[8];
    float* out = (float*)d_out;

    const int N  = in_sizes[0] / F;
    const int E1 = in_sizes[1] / 2;
    const int E2 = in_sizes[2] / 2;
    const int P  = in_sizes[5] / 2;
    const int Emax = E1 > E2 ? E1 : E2;
    const int NBIN = (N + BSZ - 1) >> BSH;      // 196 for N=100k (must be <= 1024)
    const int NGH  = NBIN * NBLKA;              // (bin,blk) cells
    const int NB   = (NGH + 1023) / 1024;       // scan blocks (<= 256)

    // workspace layout
    unsigned short* Abf = (unsigned short*)d_ws;   // N x 128 bf16 (GEMM out)
    unsigned short* Bbf = Abf + (size_t)N * F;     // N x 128 bf16 (gather-1 out)
    uintptr_t up  = (uintptr_t)(Bbf + (size_t)N * F);
    up = (up + 15) & ~(uintptr_t)15;
    float4* U       = (float4*)up;                 // N (node projections)
    int2*   ebounds = (int2*)(U + N);              // N
    int*    gh      = (int*)(ebounds + N);         // NGH
    int*    ghoffs  = gh + NGH;                    // NGH + 1
    int*    bsum    = ghoffs + NGH + 1;            // NB + 1
    uintptr_t sp  = (uintptr_t)(bsum + NB + 1);
    sp = (sp + 15) & ~(uintptr_t)15;
    uint2* Epart  = (uint2*)sp;                    // Emax (bin-partitioned edges)
    uint2* Sedge  = Epart + Emax;                  // Emax (dst-sorted edges)

    // ---- layer 1: Abf = x @ W1 ; Bbf = segment_sum over edges1 ----
    gemm128_mfma<0, 0><<<(N + 127) / 128, 256, 0, stream>>>(x, W1, Abf, N);

    binhist<<<NBLKA, 256, 0, stream>>>(ei1, gh, E1, NBIN);
    scan_pass1<<<NB, 256, 0, stream>>>(gh, bsum, NGH);
    scan_pass2<<<1, 256, 0, stream>>>(bsum, NB);
    scan_pass3<<<NB, 256, 0, stream>>>(gh, bsum, ghoffs, NGH, NB);
    binscatter<<<NBLKA, 256, 0, stream>>>(ei1, ew1, ghoffs, Epart, E1, NBIN);
    sort_bin<<<NBIN, 512, 0, stream>>>(Epart, ghoffs, Sedge, ebounds, N, NBIN);
    gather_agg<0><<<(N + 7) / 8, 256, 0, stream>>>(Abf, ebounds, Sedge, Wlin, Bbf, U, N);

    // ---- layer 2: Abf = relu(Bbf) @ W2 ; U = Wlin-projected segment_sum over edges2 ----
    gemm128_mfma<1, 1><<<(N + 127) / 128, 256, 0, stream>>>(Bbf, W2, Abf, N);

    binhist<<<NBLKA, 256, 0, stream>>>(ei2, gh, E2, NBIN);
    scan_pass1<<<NB, 256, 0, stream>>>(gh, bsum, NGH);
    scan_pass2<<<1, 256, 0, stream>>>(bsum, NB);
    scan_pass3<<<NB, 256, 0, stream>>>(gh, bsum, ghoffs, NGH, NB);
    binscatter<<<NBLKA, 256, 0, stream>>>(ei2, ew2, ghoffs, Epart, E2, NBIN);
    sort_bin<<<NBIN, 512, 0, stream>>>(Epart, ghoffs, Sedge, ebounds, N, NBIN);
    gather_agg<1><<<(N + 7) / 8, 256, 0, stream>>>(Abf, ebounds, Sedge, Wlin, Bbf, U, N);

    // ---- head: out[p] = (U[a].x + U[b].y, U[a].z + U[b].w) ----
    pair_combine<<<(P + 255) / 256, 256, 0, stream>>>(U, pos, out, P);
}

// Round 10
// 299.121 us; speedup vs baseline: 2.0912x; 1.0220x over previous
//
#include <hip/hip_runtime.h>

#define F 128
#define BSH 9            // 512 dst nodes per bin
#define BSZ 512
#define NBLKA 256        // pass-A blocks (each owns a contiguous edge chunk)

typedef __bf16 bf16x8 __attribute__((ext_vector_type(8)));
typedef unsigned short ushort8 __attribute__((ext_vector_type(8)));
typedef unsigned short ushort4v __attribute__((ext_vector_type(4)));
typedef float f32x4 __attribute__((ext_vector_type(4)));

// fp32 -> bf16 bits with round-to-nearest-even (inputs finite).
static __device__ __forceinline__ unsigned short f2bf(float f) {
    unsigned int u = __float_as_uint(f);
    u += 0x7fffu + ((u >> 16) & 1u);
    return (unsigned short)(u >> 16);
}
// packed uint (2 bf16) -> 2 floats
static __device__ __forceinline__ void bf2x(unsigned int u, float& lo, float& hi) {
    lo = __uint_as_float(u << 16);
    hi = __uint_as_float(u & 0xffff0000u);
}

#define WPITCH 136  // ushorts per WT row: 128 + 8 pad

// Y_bf16[n,128] = act(X[n,128]) @ W[128,128] via bf16 MFMA, fp32 accumulate.
template <int RELU, int INBF>
__global__ __launch_bounds__(256) void gemm128_mfma(const void* __restrict__ Xv,
                                                    const float* __restrict__ W,
                                                    unsigned short* __restrict__ Y,
                                                    int n) {
    __shared__ __align__(16) unsigned short WT[F * WPITCH];  // WT[col][k], bf16 bits
    for (int idx = threadIdx.x; idx < F * F; idx += 256) {
        const int k = idx >> 7, c = idx & 127;
        WT[c * WPITCH + k] = f2bf(W[idx]);
    }
    __syncthreads();

    const int lane = threadIdx.x & 63;
    const int wv = threadIdx.x >> 6;
    const int m15 = lane & 15;
    const int quad = lane >> 4;
    const int rowBase = blockIdx.x * 128 + wv * 32;

    f32x4 acc[2][8];
#pragma unroll
    for (int rt = 0; rt < 2; ++rt)
#pragma unroll
        for (int ct = 0; ct < 8; ++ct) acc[rt][ct] = (f32x4){0.f, 0.f, 0.f, 0.f};

    int rA[2];
    rA[0] = min(rowBase + m15, n - 1);        // clamped; stores masked below
    rA[1] = min(rowBase + 16 + m15, n - 1);

#pragma unroll
    for (int ks = 0; ks < 4; ++ks) {
        const int k0 = ks * 32 + quad * 8;    // this lane's 8-wide k window
        bf16x8 a[2];
#pragma unroll
        for (int rt = 0; rt < 2; ++rt) {
            if (INBF) {
                const unsigned short* Xb = (const unsigned short*)Xv;
                ushort8 u = *(const ushort8*)(Xb + (size_t)rA[rt] * F + k0);
                if (RELU) {
#pragma unroll
                    for (int j = 0; j < 8; ++j) u[j] = (u[j] & 0x8000u) ? 0 : u[j];
                }
                a[rt] = __builtin_bit_cast(bf16x8, u);
            } else {
                const float* Xf = (const float*)Xv;
                const float* p = Xf + (size_t)rA[rt] * F + k0;
                float4 lo = *(const float4*)p;
                float4 hi = *(const float4*)(p + 4);
                if (RELU) {
                    lo.x = fmaxf(lo.x, 0.f); lo.y = fmaxf(lo.y, 0.f);
                    lo.z = fmaxf(lo.z, 0.f); lo.w = fmaxf(lo.w, 0.f);
                    hi.x = fmaxf(hi.x, 0.f); hi.y = fmaxf(hi.y, 0.f);
                    hi.z = fmaxf(hi.z, 0.f); hi.w = fmaxf(hi.w, 0.f);
                }
                ushort8 u;
                u[0] = f2bf(lo.x); u[1] = f2bf(lo.y); u[2] = f2bf(lo.z); u[3] = f2bf(lo.w);
                u[4] = f2bf(hi.x); u[5] = f2bf(hi.y); u[6] = f2bf(hi.z); u[7] = f2bf(hi.w);
                a[rt] = __builtin_bit_cast(bf16x8, u);
            }
        }
#pragma unroll
        for (int ct = 0; ct < 8; ++ct) {
            const int nn = ct * 16 + m15;
            const bf16x8 b = *(const bf16x8*)(WT + nn * WPITCH + k0);  // ds_read_b128
            acc[0][ct] = __builtin_amdgcn_mfma_f32_16x16x32_bf16(a[0], b, acc[0][ct], 0, 0, 0);
            acc[1][ct] = __builtin_amdgcn_mfma_f32_16x16x32_bf16(a[1], b, acc[1][ct], 0, 0, 0);
        }
    }

    // C/D layout: col = lane&15, row = quad*4 + reg (within each 16x16 tile)
#pragma unroll
    for (int rt = 0; rt < 2; ++rt)
#pragma unroll
        for (int reg = 0; reg < 4; ++reg) {
            const int row = rowBase + rt * 16 + quad * 4 + reg;
            if (row < n) {
#pragma unroll
                for (int ct = 0; ct < 8; ++ct)
                    Y[(size_t)row * F + ct * 16 + m15] = f2bf(acc[rt][ct][reg]);
            }
        }
}

// --- block-rank radix partition sort of edges by destination -----------------

// Pass A1: per-block LDS histogram over bins (dst>>BSH) -> gh[bin*NBLKA + blk].
__global__ __launch_bounds__(256) void binhist(const int* __restrict__ ei,
                                               int* __restrict__ gh, int E, int nbin) {
    __shared__ int h[1024];
    for (int i = threadIdx.x; i < nbin; i += 256) h[i] = 0;
    __syncthreads();
    const int chunk = (E + NBLKA - 1) / NBLKA;
    const int lo = blockIdx.x * chunk;
    const int hi = min(lo + chunk, E);
    for (int e = lo + threadIdx.x; e < hi; e += 256)
        atomicAdd(&h[((unsigned)ei[E + e]) >> BSH], 1);
    __syncthreads();
    for (int i = threadIdx.x; i < nbin; i += 256) gh[i * NBLKA + blockIdx.x] = h[i];
}

// 3-stage exact scan over the (bin,blk) cells.
__global__ __launch_bounds__(256) void scan_pass1(const int* __restrict__ counts,
                                                  int* __restrict__ bsum, int n) {
    __shared__ int sh[256];
    const int base = blockIdx.x * 1024 + threadIdx.x * 4;
    int s = 0;
#pragma unroll
    for (int j = 0; j < 4; ++j) {
        const int i = base + j;
        if (i < n) s += counts[i];
    }
    sh[threadIdx.x] = s;
    __syncthreads();
    for (int off = 128; off > 0; off >>= 1) {
        if (threadIdx.x < off) sh[threadIdx.x] += sh[threadIdx.x + off];
        __syncthreads();
    }
    if (threadIdx.x == 0) bsum[blockIdx.x] = sh[0];
}

__global__ __launch_bounds__(256) void scan_pass2(int* __restrict__ bsum, int nb) {
    __shared__ int sh[256];
    int v = (threadIdx.x < nb) ? bsum[threadIdx.x] : 0;
    sh[threadIdx.x] = v;
    __syncthreads();
    for (int off = 1; off < 256; off <<= 1) {
        int t = (threadIdx.x >= off) ? sh[threadIdx.x - off] : 0;
        __syncthreads();
        sh[threadIdx.x] += t;
        __syncthreads();
    }
    if (threadIdx.x < nb) bsum[threadIdx.x] = sh[threadIdx.x] - v;  // exclusive
    if (threadIdx.x == nb) bsum[nb] = sh[nb - 1];                   // total
}

__global__ __launch_bounds__(256) void scan_pass3(const int* __restrict__ counts,
                                                  const int* __restrict__ bsum,
                                                  int* __restrict__ offs,
                                                  int n, int nb) {
    __shared__ int sh[256];
    const int base = blockIdx.x * 1024 + threadIdx.x * 4;
    int c[4];
    int s = 0;
#pragma unroll
    for (int j = 0; j < 4; ++j) {
        const int i = base + j;
        c[j] = (i < n) ? counts[i] : 0;
        s += c[j];
    }
    int inc = s;
    sh[threadIdx.x] = inc;
    __syncthreads();
    for (int off = 1; off < 256; off <<= 1) {
        int t = (threadIdx.x >= off) ? sh[threadIdx.x - off] : 0;
        __syncthreads();
        sh[threadIdx.x] += t;
        __syncthreads();
    }
    int run = bsum[blockIdx.x] + sh[threadIdx.x] - inc;
#pragma unroll
    for (int j = 0; j < 4; ++j) {
        const int i = base + j;
        if (i < n) offs[i] = run;
        run += c[j];
    }
    if (blockIdx.x == 0 && threadIdx.x == 0) offs[n] = bsum[nb];
}

// Pass A3: re-read chunk, append each edge into this block's reserved run for
// its bin (contiguous runs -> full-line writes, no global atomics).
// Payload: (src | dstLocal<<20, w-bits). src < 2^20, dstLocal < 512.
__global__ __launch_bounds__(256) void binscatter(const int* __restrict__ ei,
                                                  const float* __restrict__ ew,
                                                  const int* __restrict__ ghoffs,
                                                  uint2* __restrict__ Epart,
                                                  int E, int nbin) {
    __shared__ int gbase[1024];
    __shared__ int cur[1024];
    for (int i = threadIdx.x; i < nbin; i += 256) {
        gbase[i] = ghoffs[i * NBLKA + blockIdx.x];
        cur[i] = 0;
    }
    __syncthreads();
    const int chunk = (E + NBLKA - 1) / NBLKA;
    const int lo = blockIdx.x * chunk;
    const int hi = min(lo + chunk, E);
    for (int e = lo + threadIdx.x; e < hi; e += 256) {
        const unsigned int dst = (unsigned int)ei[E + e];
        const unsigned int src = (unsigned int)ei[e];
        const int b = (int)(dst >> BSH);
        const int r = atomicAdd(&cur[b], 1);
        Epart[(size_t)gbase[b] + r] =
            make_uint2(src | ((dst & (BSZ - 1)) << 20), (unsigned)__float_as_int(ew[e]));
    }
}

// Pass B: one block per bin; LDS hist/scan/rank over 512 local dsts; scatter
// within the bin's own span (single-block locality); emit ebounds.
__global__ __launch_bounds__(512) void sort_bin(const uint2* __restrict__ Epart,
                                                const int* __restrict__ ghoffs,
                                                uint2* __restrict__ Sedge,
                                                int2* __restrict__ ebounds,
                                                int n, int nbin) {
    __shared__ int hist[BSZ], pref[BSZ], cur[BSZ];
    const int bin = blockIdx.x;
    const int tid = threadIdx.x;
    const int base = ghoffs[bin * NBLKA];
    const int end  = ghoffs[(bin + 1) * NBLKA];  // bin==nbin-1 hits the sentinel
    hist[tid] = 0;
    __syncthreads();
    for (int i = base + tid; i < end; i += 512)
        atomicAdd(&hist[Epart[i].x >> 20], 1);
    __syncthreads();
    pref[tid] = hist[tid];
    __syncthreads();
    for (int off = 1; off < BSZ; off <<= 1) {
        int t = (tid >= off) ? pref[tid - off] : 0;
        __syncthreads();
        pref[tid] += t;
        __syncthreads();
    }
    {
        const int inc = pref[tid];
        const int ex = inc - hist[tid];
        cur[tid] = ex;
        const int v = (bin << BSH) + tid;
        if (v < n) ebounds[v] = make_int2(base + ex, base + inc);
    }
    __syncthreads();
    for (int i = base + tid; i < end; i += 512) {
        const uint2 e = Epart[i];
        const int pos = atomicAdd(&cur[e.x >> 20], 1);
        Sedge[(size_t)base + pos] = make_uint2(e.x & 0xFFFFFu, e.y);
    }
}

// OUT[v] = sum over incoming edges w_e * XW_bf16[src_e].
// 16 lanes per node; each lane covers 8 features via one uint4 (16B) load ->
// one dwordx4 burst covers the whole 256B row; 4 nodes/wave, unroll x4 = 4KB
// in flight per wave. FUSE_U == 1: project fp32 row onto Wlin, write U[v].
template <int FUSE_U>
__global__ __launch_bounds__(256) void gather_agg(const unsigned short* __restrict__ XW,
                                                  const int2* __restrict__ ebounds,
                                                  const uint2* __restrict__ Sedge,
                                                  const float* __restrict__ Wlin,
                                                  unsigned short* __restrict__ OUT,
                                                  float4* __restrict__ U, int n) {
    __shared__ float WL[512];
    if (FUSE_U) {
        for (int i = threadIdx.x; i < 512; i += 256) WL[i] = Wlin[i];
        __syncthreads();
    }
    const int l = threadIdx.x & 15;              // 16 lanes per node
    const int v = blockIdx.x * 16 + (threadIdx.x >> 4);
    if (v >= n) return;
    float acc[8];
#pragma unroll
    for (int j = 0; j < 8; ++j) acc[j] = 0.f;
    const int2 be = ebounds[v];
    int p = be.x;
    const int e2 = be.y;
    for (; p + 4 <= e2; p += 4) {
        const uint2 s0 = Sedge[p],     s1 = Sedge[p + 1];
        const uint2 s2 = Sedge[p + 2], s3 = Sedge[p + 3];
        const uint4 x0 = ((const uint4*)(XW + (size_t)s0.x * F))[l];
        const uint4 x1 = ((const uint4*)(XW + (size_t)s1.x * F))[l];
        const uint4 x2 = ((const uint4*)(XW + (size_t)s2.x * F))[l];
        const uint4 x3 = ((const uint4*)(XW + (size_t)s3.x * F))[l];
        const float w0 = __int_as_float(s0.y), w1 = __int_as_float(s1.y);
        const float w2 = __int_as_float(s2.y), w3 = __int_as_float(s3.y);
        float a0, a1, a2, a3, a4, a5, a6, a7;
        bf2x(x0.x, a0, a1); bf2x(x0.y, a2, a3); bf2x(x0.z, a4, a5); bf2x(x0.w, a6, a7);
        acc[0] = fmaf(w0, a0, acc[0]); acc[1] = fmaf(w0, a1, acc[1]);
        acc[2] = fmaf(w0, a2, acc[2]); acc[3] = fmaf(w0, a3, acc[3]);
        acc[4] = fmaf(w0, a4, acc[4]); acc[5] = fmaf(w0, a5, acc[5]);
        acc[6] = fmaf(w0, a6, acc[6]); acc[7] = fmaf(w0, a7, acc[7]);
        bf2x(x1.x, a0, a1); bf2x(x1.y, a2, a3); bf2x(x1.z, a4, a5); bf2x(x1.w, a6, a7);
        acc[0] = fmaf(w1, a0, acc[0]); acc[1] = fmaf(w1, a1, acc[1]);
        acc[2] = fmaf(w1, a2, acc[2]); acc[3] = fmaf(w1, a3, acc[3]);
        acc[4] = fmaf(w1, a4, acc[4]); acc[5] = fmaf(w1, a5, acc[5]);
        acc[6] = fmaf(w1, a6, acc[6]); acc[7] = fmaf(w1, a7, acc[7]);
        bf2x(x2.x, a0, a1); bf2x(x2.y, a2, a3); bf2x(x2.z, a4, a5); bf2x(x2.w, a6, a7);
        acc[0] = fmaf(w2, a0, acc[0]); acc[1] = fmaf(w2, a1, acc[1]);
        acc[2] = fmaf(w2, a2, acc[2]); acc[3] = fmaf(w2, a3, acc[3]);
        acc[4] = fmaf(w2, a4, acc[4]); acc[5] = fmaf(w2, a5, acc[5]);
        acc[6] = fmaf(w2, a6, acc[6]); acc[7] = fmaf(w2, a7, acc[7]);
        bf2x(x3.x, a0, a1); bf2x(x3.y, a2, a3); bf2x(x3.z, a4, a5); bf2x(x3.w, a6, a7);
        acc[0] = fmaf(w3, a0, acc[0]); acc[1] = fmaf(w3, a1, acc[1]);
        acc[2] = fmaf(w3, a2, acc[2]); acc[3] = fmaf(w3, a3, acc[3]);
        acc[4] = fmaf(w3, a4, acc[4]); acc[5] = fmaf(w3, a5, acc[5]);
        acc[6] = fmaf(w3, a6, acc[6]); acc[7] = fmaf(w3, a7, acc[7]);
    }
    for (; p < e2; ++p) {
        const uint2 s = Sedge[p];
        const float w = __int_as_float(s.y);
        const uint4 x = ((const uint4*)(XW + (size_t)s.x * F))[l];
        float a0, a1, a2, a3, a4, a5, a6, a7;
        bf2x(x.x, a0, a1); bf2x(x.y, a2, a3); bf2x(x.z, a4, a5); bf2x(x.w, a6, a7);
        acc[0] = fmaf(w, a0, acc[0]); acc[1] = fmaf(w, a1, acc[1]);
        acc[2] = fmaf(w, a2, acc[2]); acc[3] = fmaf(w, a3, acc[3]);
        acc[4] = fmaf(w, a4, acc[4]); acc[5] = fmaf(w, a5, acc[5]);
        acc[6] = fmaf(w, a6, acc[6]); acc[7] = fmaf(w, a7, acc[7]);
    }
    if (!FUSE_U) {
        ushort8 o;
#pragma unroll
        for (int j = 0; j < 8; ++j) o[j] = f2bf(acc[j]);
        *(ushort8*)(OUT + (size_t)v * F + (size_t)l * 8) = o;
    } else {
        const int k = l * 8;
        float s0 = 0.f, s1 = 0.f, s2 = 0.f, s3 = 0.f;
#pragma unroll
        for (int j = 0; j < 8; ++j) {
            s0 = fmaf(acc[j], WL[k + j],       s0);
            s1 = fmaf(acc[j], WL[128 + k + j], s1);
            s2 = fmaf(acc[j], WL[256 + k + j], s2);
            s3 = fmaf(acc[j], WL[384 + k + j], s3);
        }
#pragma unroll
        for (int off = 8; off > 0; off >>= 1) {
            s0 += __shfl_down(s0, off, 16);
            s1 += __shfl_down(s1, off, 16);
            s2 += __shfl_down(s2, off, 16);
            s3 += __shfl_down(s3, off, 16);
        }
        if (l == 0) U[v] = make_float4(s0, s1, s2, s3);
    }
}

// out[p,:] = (U[a].x + U[b].y, U[a].z + U[b].w); one thread per pair.
__global__ __launch_bounds__(256) void pair_combine(const float4* __restrict__ U,
                                                    const int* __restrict__ pos,
                                                    float* __restrict__ out, int P) {
    const int p = blockIdx.x * 256 + threadIdx.x;
    if (p >= P) return;
    const int a = pos[p];
    const int b = pos[P + p];
    const float4 ua = U[a];
    const float4 ub = U[b];
    *(float2*)(out + (size_t)p * 2) = make_float2(ua.x + ub.y, ua.z + ub.w);
}

extern "C" void kernel_launch(void* const* d_in, const int* in_sizes, int n_in,
                              void* d_out, int out_size, void* d_ws, size_t ws_size,
                              hipStream_t stream) {
    const float* x    = (const float*)d_in[0];
    const int*   ei1  = (const int*)  d_in[1];
    const int*   ei2  = (const int*)  d_in[2];
    const float* ew1  = (const float*)d_in[3];
    const float* ew2  = (const float*)d_in[4];
    const int*   pos  = (const int*)  d_in[5];
    const float* W1   = (const float*)d_in[6];
    const float* W2   = (const float*)d_in[7];
    const float* Wlin = (const float*)d_in[8];
    float* out = (float*)d_out;

    const int N  = in_sizes[0] / F;
    const int E1 = in_sizes[1] / 2;
    const int E2 = in_sizes[2] / 2;
    const int P  = in_sizes[5] / 2;
    const int Emax = E1 > E2 ? E1 : E2;
    const int NBIN = (N + BSZ - 1) >> BSH;      // 196 for N=100k (must be <= 1024)
    const int NGH  = NBIN * NBLKA;              // (bin,blk) cells
    const int NB   = (NGH + 1023) / 1024;       // scan blocks (<= 256)

    // workspace layout
    unsigned short* Abf = (unsigned short*)d_ws;   // N x 128 bf16 (GEMM out)
    unsigned short* Bbf = Abf + (size_t)N * F;     // N x 128 bf16 (gather-1 out)
    uintptr_t up  = (uintptr_t)(Bbf + (size_t)N * F);
    up = (up + 15) & ~(uintptr_t)15;
    float4* U       = (float4*)up;                 // N (node projections)
    int2*   ebounds = (int2*)(U + N);              // N
    int*    gh      = (int*)(ebounds + N);         // NGH
    int*    ghoffs  = gh + NGH;                    // NGH + 1
    int*    bsum    = ghoffs + NGH + 1;            // NB + 1
    uintptr_t sp  = (uintptr_t)(bsum + NB + 1);
    sp = (sp + 15) & ~(uintptr_t)15;
    uint2* Epart  = (uint2*)sp;                    // Emax (bin-partitioned edges)
    uint2* Sedge  = Epart + Emax;                  // Emax (dst-sorted edges)

    // ---- layer 1: Abf = x @ W1 ; Bbf = segment_sum over edges1 ----
    gemm128_mfma<0, 0><<<(N + 127) / 128, 256, 0, stream>>>(x, W1, Abf, N);

    binhist<<<NBLKA, 256, 0, stream>>>(ei1, gh, E1, NBIN);
    scan_pass1<<<NB, 256, 0, stream>>>(gh, bsum, NGH);
    scan_pass2<<<1, 256, 0, stream>>>(bsum, NB);
    scan_pass3<<<NB, 256, 0, stream>>>(gh, bsum, ghoffs, NGH, NB);
    binscatter<<<NBLKA, 256, 0, stream>>>(ei1, ew1, ghoffs, Epart, E1, NBIN);
    sort_bin<<<NBIN, 512, 0, stream>>>(Epart, ghoffs, Sedge, ebounds, N, NBIN);
    gather_agg<0><<<(N + 15) / 16, 256, 0, stream>>>(Abf, ebounds, Sedge, Wlin, Bbf, U, N);

    // ---- layer 2: Abf = relu(Bbf) @ W2 ; U = Wlin-projected segment_sum over edges2 ----
    gemm128_mfma<1, 1><<<(N + 127) / 128, 256, 0, stream>>>(Bbf, W2, Abf, N);

    binhist<<<NBLKA, 256, 0, stream>>>(ei2, gh, E2, NBIN);
    scan_pass1<<<NB, 256, 0, stream>>>(gh, bsum, NGH);
    scan_pass2<<<1, 256, 0, stream>>>(bsum, NB);
    scan_pass3<<<NB, 256, 0, stream>>>(gh, bsum, ghoffs, NGH, NB);
    binscatter<<<NBLKA, 256, 0, stream>>>(ei2, ew2, ghoffs, Epart, E2, NBIN);
    sort_bin<<<NBIN, 512, 0, stream>>>(Epart, ghoffs, Sedge, ebounds, N, NBIN);
    gather_agg<1><<<(N + 15) / 16, 256, 0, stream>>>(Abf, ebounds, Sedge, Wlin, Bbf, U, N);

    // ---- head: out[p] = (U[a].x + U[b].y, U[a].z + U[b].w) ----
    pair_combine<<<(P + 255) / 256, 256, 0, stream>>>(U, pos, out, P);
}

// Round 11
// 254.207 us; speedup vs baseline: 2.4606x; 1.1767x over previous
//
#include <hip/hip_runtime.h>

#define F 128
#define BSH 9            // 512 dst nodes per bin
#define BSZ 512
#define NBLKA 256        // scatter blocks per layer
#define MAXBIN 256       // upper bound on bins (N <= 131072)
#define CSTRIDE 16       // bincur stride in ints (one counter per 64B line)

typedef __bf16 bf16x8 __attribute__((ext_vector_type(8)));
typedef unsigned short ushort8 __attribute__((ext_vector_type(8)));
typedef float f32x4 __attribute__((ext_vector_type(4)));

// fp32 -> bf16 bits with round-to-nearest-even (inputs finite).
static __device__ __forceinline__ unsigned short f2bf(float f) {
    unsigned int u = __float_as_uint(f);
    u += 0x7fffu + ((u >> 16) & 1u);
    return (unsigned short)(u >> 16);
}
// packed uint (2 bf16) -> 2 floats
static __device__ __forceinline__ void bf2x(unsigned int u, float& lo, float& hi) {
    lo = __uint_as_float(u << 16);
    hi = __uint_as_float(u & 0xffff0000u);
}

#define WPITCH 136  // ushorts per WT row: 128 + 8 pad

// Y_bf16[n,128] = act(X[n,128]) @ W[128,128] via bf16 MFMA, fp32 accumulate.
// Side effect: blocks 0/1 zero z1/z2 (cursor arrays for the later sort) when zn>0.
template <int RELU, int INBF>
__global__ __launch_bounds__(256) void gemm128_mfma(const void* __restrict__ Xv,
                                                    const float* __restrict__ W,
                                                    unsigned short* __restrict__ Y,
                                                    int n,
                                                    int* __restrict__ z1,
                                                    int* __restrict__ z2, int zn) {
    if (zn > 0) {
        if (blockIdx.x == 0) { for (int i = threadIdx.x; i < zn; i += 256) z1[i] = 0; }
        else if (blockIdx.x == 1) { for (int i = threadIdx.x; i < zn; i += 256) z2[i] = 0; }
    }
    __shared__ __align__(16) unsigned short WT[F * WPITCH];  // WT[col][k], bf16 bits
    for (int idx = threadIdx.x; idx < F * F; idx += 256) {
        const int k = idx >> 7, c = idx & 127;
        WT[c * WPITCH + k] = f2bf(W[idx]);
    }
    __syncthreads();

    const int lane = threadIdx.x & 63;
    const int wv = threadIdx.x >> 6;
    const int m15 = lane & 15;
    const int quad = lane >> 4;
    const int rowBase = blockIdx.x * 128 + wv * 32;

    f32x4 acc[2][8];
#pragma unroll
    for (int rt = 0; rt < 2; ++rt)
#pragma unroll
        for (int ct = 0; ct < 8; ++ct) acc[rt][ct] = (f32x4){0.f, 0.f, 0.f, 0.f};

    int rA[2];
    rA[0] = min(rowBase + m15, n - 1);        // clamped; stores masked below
    rA[1] = min(rowBase + 16 + m15, n - 1);

#pragma unroll
    for (int ks = 0; ks < 4; ++ks) {
        const int k0 = ks * 32 + quad * 8;    // this lane's 8-wide k window
        bf16x8 a[2];
#pragma unroll
        for (int rt = 0; rt < 2; ++rt) {
            if (INBF) {
                const unsigned short* Xb = (const unsigned short*)Xv;
                ushort8 u = *(const ushort8*)(Xb + (size_t)rA[rt] * F + k0);
                if (RELU) {
#pragma unroll
                    for (int j = 0; j < 8; ++j) u[j] = (u[j] & 0x8000u) ? 0 : u[j];
                }
                a[rt] = __builtin_bit_cast(bf16x8, u);
            } else {
                const float* Xf = (const float*)Xv;
                const float* p = Xf + (size_t)rA[rt] * F + k0;
                float4 lo = *(const float4*)p;
                float4 hi = *(const float4*)(p + 4);
                if (RELU) {
                    lo.x = fmaxf(lo.x, 0.f); lo.y = fmaxf(lo.y, 0.f);
                    lo.z = fmaxf(lo.z, 0.f); lo.w = fmaxf(lo.w, 0.f);
                    hi.x = fmaxf(hi.x, 0.f); hi.y = fmaxf(hi.y, 0.f);
                    hi.z = fmaxf(hi.z, 0.f); hi.w = fmaxf(hi.w, 0.f);
                }
                ushort8 u;
                u[0] = f2bf(lo.x); u[1] = f2bf(lo.y); u[2] = f2bf(lo.z); u[3] = f2bf(lo.w);
                u[4] = f2bf(hi.x); u[5] = f2bf(hi.y); u[6] = f2bf(hi.z); u[7] = f2bf(hi.w);
                a[rt] = __builtin_bit_cast(bf16x8, u);
            }
        }
#pragma unroll
        for (int ct = 0; ct < 8; ++ct) {
            const int nn = ct * 16 + m15;
            const bf16x8 b = *(const bf16x8*)(WT + nn * WPITCH + k0);  // ds_read_b128
            acc[0][ct] = __builtin_amdgcn_mfma_f32_16x16x32_bf16(a[0], b, acc[0][ct], 0, 0, 0);
            acc[1][ct] = __builtin_amdgcn_mfma_f32_16x16x32_bf16(a[1], b, acc[1][ct], 0, 0, 0);
        }
    }

    // C/D layout: col = lane&15, row = quad*4 + reg (within each 16x16 tile)
#pragma unroll
    for (int rt = 0; rt < 2; ++rt)
#pragma unroll
        for (int reg = 0; reg < 4; ++reg) {
            const int row = rowBase + rt * 16 + quad * 4 + reg;
            if (row < n) {
#pragma unroll
                for (int ct = 0; ct < 8; ++ct)
                    Y[(size_t)row * F + ct * 16 + m15] = f2bf(acc[rt][ct][reg]);
            }
        }
}

// --- single-kernel bin partition (both layers), fixed-capacity bins ----------
// Per block: LDS histogram of its chunk, one bulk atomicAdd per (block,bin) on
// line-strided global cursors, then append into the reserved runs.
__global__ __launch_bounds__(256) void scatter_both(
    const int* __restrict__ ei1, const float* __restrict__ ew1,
    const int* __restrict__ ei2, const float* __restrict__ ew2,
    int* __restrict__ bc1, int* __restrict__ bc2,
    uint2* __restrict__ Ep1, uint2* __restrict__ Ep2,
    int E1, int E2, int nbin, int cap) {
    __shared__ int h[MAXBIN], base[MAXBIN], cur[MAXBIN];
    const int layer2 = blockIdx.x >= NBLKA;
    const int blk = layer2 ? blockIdx.x - NBLKA : blockIdx.x;
    const int* __restrict__ ei = layer2 ? ei2 : ei1;
    const float* __restrict__ ew = layer2 ? ew2 : ew1;
    int* __restrict__ bc = layer2 ? bc2 : bc1;
    uint2* __restrict__ Ep = layer2 ? Ep2 : Ep1;
    const int E = layer2 ? E2 : E1;

    for (int i = threadIdx.x; i < nbin; i += 256) h[i] = 0;
    __syncthreads();
    const int chunk = (E + NBLKA - 1) / NBLKA;
    const int lo = blk * chunk;
    const int hi = min(lo + chunk, E);
    for (int e = lo + threadIdx.x; e < hi; e += 256)
        atomicAdd(&h[((unsigned)ei[E + e]) >> BSH], 1);
    __syncthreads();
    for (int i = threadIdx.x; i < nbin; i += 256) {
        cur[i] = 0;
        base[i] = h[i] ? atomicAdd(&bc[i * CSTRIDE], h[i]) : 0;
    }
    __syncthreads();
    for (int e = lo + threadIdx.x; e < hi; e += 256) {
        const unsigned int dst = (unsigned int)ei[E + e];
        const unsigned int src = (unsigned int)ei[e];
        const int b = (int)(dst >> BSH);
        const int slot = base[b] + atomicAdd(&cur[b], 1);
        if (slot < cap)   // statistically impossible overflow; memory-safety guard
            Ep[(size_t)b * cap + slot] =
                make_uint2(src | ((dst & (BSZ - 1)) << 20), (unsigned)__float_as_int(ew[e]));
    }
}

// One block per (layer, bin): LDS hist/scan/rank over 512 local dsts; scatter
// within the bin's own fixed span; emit ebounds.
__global__ __launch_bounds__(512) void sort_both(
    const uint2* __restrict__ Ep1, const uint2* __restrict__ Ep2,
    const int* __restrict__ bc1, const int* __restrict__ bc2,
    uint2* __restrict__ Sg1, uint2* __restrict__ Sg2,
    int2* __restrict__ eb1, int2* __restrict__ eb2,
    int n, int nbin, int cap) {
    __shared__ int hist[BSZ], pref[BSZ], cur[BSZ];
    const int layer2 = blockIdx.x >= nbin;
    const int bin = layer2 ? blockIdx.x - nbin : blockIdx.x;
    const uint2* __restrict__ Ep = layer2 ? Ep2 : Ep1;
    const int* __restrict__ bc = layer2 ? bc2 : bc1;
    uint2* __restrict__ Sg = layer2 ? Sg2 : Sg1;
    int2* __restrict__ eb = layer2 ? eb2 : eb1;
    const int tid = threadIdx.x;
    const int base = bin * cap;
    const int cnt = min(bc[bin * CSTRIDE], cap);
    hist[tid] = 0;
    __syncthreads();
    for (int i = tid; i < cnt; i += 512)
        atomicAdd(&hist[Ep[(size_t)base + i].x >> 20], 1);
    __syncthreads();
    pref[tid] = hist[tid];
    __syncthreads();
    for (int off = 1; off < BSZ; off <<= 1) {
        int t = (tid >= off) ? pref[tid - off] : 0;
        __syncthreads();
        pref[tid] += t;
        __syncthreads();
    }
    {
        const int inc = pref[tid];
        const int ex = inc - hist[tid];
        cur[tid] = ex;
        const int v = (bin << BSH) + tid;
        if (v < n) eb[v] = make_int2(base + ex, base + inc);
    }
    __syncthreads();
    for (int i = tid; i < cnt; i += 512) {
        const uint2 e = Ep[(size_t)base + i];
        const int pos = atomicAdd(&cur[e.x >> 20], 1);
        Sg[(size_t)base + pos] = make_uint2(e.x & 0xFFFFFu, e.y);
    }
}

// OUT[v] = sum over incoming edges w_e * XW_bf16[src_e].
// 16 lanes per node, uint4 per lane (full 256B row per group). Masked quads:
// every edge goes through a depth-4 MLP window (no depth-1 remainder).
// FUSE_U == 1: project fp32 row onto Wlin, write U[v] instead of the row.
template <int FUSE_U>
__global__ __launch_bounds__(256) void gather_agg(const unsigned short* __restrict__ XW,
                                                  const int2* __restrict__ ebounds,
                                                  const uint2* __restrict__ Sedge,
                                                  const float* __restrict__ Wlin,
                                                  unsigned short* __restrict__ OUT,
                                                  float4* __restrict__ U, int n) {
    __shared__ float WL[512];
    if (FUSE_U) {
        for (int i = threadIdx.x; i < 512; i += 256) WL[i] = Wlin[i];
        __syncthreads();
    }
    const int l = threadIdx.x & 15;              // 16 lanes per node
    const int v = blockIdx.x * 16 + (threadIdx.x >> 4);
    if (v >= n) return;
    float acc[8];
#pragma unroll
    for (int j = 0; j < 8; ++j) acc[j] = 0.f;
    const int2 be = ebounds[v];
    const int e2 = be.y;
    for (int p = be.x; p < e2; p += 4) {
        const int p1 = min(p + 1, e2 - 1);
        const int p2 = min(p + 2, e2 - 1);
        const int p3 = min(p + 3, e2 - 1);
        const uint2 s0 = Sedge[p],  s1 = Sedge[p1];
        const uint2 s2 = Sedge[p2], s3 = Sedge[p3];
        const uint4 x0 = ((const uint4*)(XW + (size_t)s0.x * F))[l];
        const uint4 x1 = ((const uint4*)(XW + (size_t)s1.x * F))[l];
        const uint4 x2 = ((const uint4*)(XW + (size_t)s2.x * F))[l];
        const uint4 x3 = ((const uint4*)(XW + (size_t)s3.x * F))[l];
        const float w0 = __int_as_float(s0.y);
        const float w1 = (p + 1 < e2) ? __int_as_float(s1.y) : 0.f;
        const float w2 = (p + 2 < e2) ? __int_as_float(s2.y) : 0.f;
        const float w3 = (p + 3 < e2) ? __int_as_float(s3.y) : 0.f;
        float a0, a1, a2, a3, a4, a5, a6, a7;
        bf2x(x0.x, a0, a1); bf2x(x0.y, a2, a3); bf2x(x0.z, a4, a5); bf2x(x0.w, a6, a7);
        acc[0] = fmaf(w0, a0, acc[0]); acc[1] = fmaf(w0, a1, acc[1]);
        acc[2] = fmaf(w0, a2, acc[2]); acc[3] = fmaf(w0, a3, acc[3]);
        acc[4] = fmaf(w0, a4, acc[4]); acc[5] = fmaf(w0, a5, acc[5]);
        acc[6] = fmaf(w0, a6, acc[6]); acc[7] = fmaf(w0, a7, acc[7]);
        bf2x(x1.x, a0, a1); bf2x(x1.y, a2, a3); bf2x(x1.z, a4, a5); bf2x(x1.w, a6, a7);
        acc[0] = fmaf(w1, a0, acc[0]); acc[1] = fmaf(w1, a1, acc[1]);
        acc[2] = fmaf(w1, a2, acc[2]); acc[3] = fmaf(w1, a3, acc[3]);
        acc[4] = fmaf(w1, a4, acc[4]); acc[5] = fmaf(w1, a5, acc[5]);
        acc[6] = fmaf(w1, a6, acc[6]); acc[7] = fmaf(w1, a7, acc[7]);
        bf2x(x2.x, a0, a1); bf2x(x2.y, a2, a3); bf2x(x2.z, a4, a5); bf2x(x2.w, a6, a7);
        acc[0] = fmaf(w2, a0, acc[0]); acc[1] = fmaf(w2, a1, acc[1]);
        acc[2] = fmaf(w2, a2, acc[2]); acc[3] = fmaf(w2, a3, acc[3]);
        acc[4] = fmaf(w2, a4, acc[4]); acc[5] = fmaf(w2, a5, acc[5]);
        acc[6] = fmaf(w2, a6, acc[6]); acc[7] = fmaf(w2, a7, acc[7]);
        bf2x(x3.x, a0, a1); bf2x(x3.y, a2, a3); bf2x(x3.z, a4, a5); bf2x(x3.w, a6, a7);
        acc[0] = fmaf(w3, a0, acc[0]); acc[1] = fmaf(w3, a1, acc[1]);
        acc[2] = fmaf(w3, a2, acc[2]); acc[3] = fmaf(w3, a3, acc[3]);
        acc[4] = fmaf(w3, a4, acc[4]); acc[5] = fmaf(w3, a5, acc[5]);
        acc[6] = fmaf(w3, a6, acc[6]); acc[7] = fmaf(w3, a7, acc[7]);
    }
    if (!FUSE_U) {
        ushort8 o;
#pragma unroll
        for (int j = 0; j < 8; ++j) o[j] = f2bf(acc[j]);
        *(ushort8*)(OUT + (size_t)v * F + (size_t)l * 8) = o;
    } else {
        const int k = l * 8;
        float s0 = 0.f, s1 = 0.f, s2 = 0.f, s3 = 0.f;
#pragma unroll
        for (int j = 0; j < 8; ++j) {
            s0 = fmaf(acc[j], WL[k + j],       s0);
            s1 = fmaf(acc[j], WL[128 + k + j], s1);
            s2 = fmaf(acc[j], WL[256 + k + j], s2);
            s3 = fmaf(acc[j], WL[384 + k + j], s3);
        }
#pragma unroll
        for (int off = 8; off > 0; off >>= 1) {
            s0 += __shfl_down(s0, off, 16);
            s1 += __shfl_down(s1, off, 16);
            s2 += __shfl_down(s2, off, 16);
            s3 += __shfl_down(s3, off, 16);
        }
        if (l == 0) U[v] = make_float4(s0, s1, s2, s3);
    }
}

// out[p,:] = (U[a].x + U[b].y, U[a].z + U[b].w); one thread per pair.
__global__ __launch_bounds__(256) void pair_combine(const float4* __restrict__ U,
                                                    const int* __restrict__ pos,
                                                    float* __restrict__ out, int P) {
    const int p = blockIdx.x * 256 + threadIdx.x;
    if (p >= P) return;
    const int a = pos[p];
    const int b = pos[P + p];
    const float4 ua = U[a];
    const float4 ub = U[b];
    *(float2*)(out + (size_t)p * 2) = make_float2(ua.x + ub.y, ua.z + ub.w);
}

extern "C" void kernel_launch(void* const* d_in, const int* in_sizes, int n_in,
                              void* d_out, int out_size, void* d_ws, size_t ws_size,
                              hipStream_t stream) {
    const float* x    = (const float*)d_in[0];
    const int*   ei1  = (const int*)  d_in[1];
    const int*   ei2  = (const int*)  d_in[2];
    const float* ew1  = (const float*)d_in[3];
    const float* ew2  = (const float*)d_in[4];
    const int*   pos  = (const int*)  d_in[5];
    const float* W1   = (const float*)d_in[6];
    const float* W2   = (const float*)d_in[7];
    const float* Wlin = (const float*)d_in[8];
    float* out = (float*)d_out;

    const int N  = in_sizes[0] / F;
    const int E1 = in_sizes[1] / 2;
    const int E2 = in_sizes[2] / 2;
    const int P  = in_sizes[5] / 2;
    const int Emax = E1 > E2 ? E1 : E2;
    const int NBIN = (N + BSZ - 1) >> BSH;          // 196 for N=100k (<= MAXBIN)
    const int cap  = Emax / NBIN + 512;             // ~avg + 8 sigma

    // workspace layout
    unsigned short* Abf = (unsigned short*)d_ws;    // N x 128 bf16 (GEMM out)
    unsigned short* Bbf = Abf + (size_t)N * F;      // N x 128 bf16 (gather-1 out)
    uintptr_t up  = (uintptr_t)(Bbf + (size_t)N * F);
    up = (up + 15) & ~(uintptr_t)15;
    float4* U     = (float4*)up;                    // N (node projections)
    int2*   eb1   = (int2*)(U + N);                 // N
    int2*   eb2   = eb1 + N;                        // N
    int*    bc1   = (int*)(eb2 + N);                // NBIN * CSTRIDE (line-strided)
    int*    bc2   = bc1 + NBIN * CSTRIDE;           // NBIN * CSTRIDE
    uintptr_t sp  = (uintptr_t)(bc2 + NBIN * CSTRIDE);
    sp = (sp + 15) & ~(uintptr_t)15;
    uint2* Ep1   = (uint2*)sp;                      // NBIN*cap
    uint2* Sg1   = Ep1 + (size_t)NBIN * cap;        // NBIN*cap
    uint2* Ep2   = Sg1 + (size_t)NBIN * cap;        // NBIN*cap
    uint2* Sg2   = Ep2 + (size_t)NBIN * cap;        // NBIN*cap

    // 1) Abf = x @ W1 (also zeroes both layers' bin cursors)
    gemm128_mfma<0, 0><<<(N + 127) / 128, 256, 0, stream>>>(
        x, W1, Abf, N, bc1, bc2, NBIN * CSTRIDE);
    // 2) partition both edge lists into fixed-capacity bins
    scatter_both<<<2 * NBLKA, 256, 0, stream>>>(
        ei1, ew1, ei2, ew2, bc1, bc2, Ep1, Ep2, E1, E2, NBIN, cap);
    // 3) dst-sort both layers' bins, emit ebounds
    sort_both<<<2 * NBIN, 512, 0, stream>>>(
        Ep1, Ep2, bc1, bc2, Sg1, Sg2, eb1, eb2, N, NBIN, cap);
    // 4) Bbf = segment_sum over edges1
    gather_agg<0><<<(N + 15) / 16, 256, 0, stream>>>(Abf, eb1, Sg1, Wlin, Bbf, U, N);
    // 5) Abf = relu(Bbf) @ W2
    gemm128_mfma<1, 1><<<(N + 127) / 128, 256, 0, stream>>>(
        Bbf, W2, Abf, N, nullptr, nullptr, 0);
    // 6) U = Wlin-projected segment_sum over edges2
    gather_agg<1><<<(N + 15) / 16, 256, 0, stream>>>(Abf, eb2, Sg2, Wlin, Bbf, U, N);
    // 7) head
    pair_combine<<<(P + 255) / 256, 256, 0, stream>>>(U, pos, out, P);
}

// Round 12
// 245.445 us; speedup vs baseline: 2.5485x; 1.0357x over previous
//
#include <hip/hip_runtime.h>

#define F 128
#define BSH 9            // 512 dst nodes per bin
#define BSZ 512
#define NBLKA 256        // scatter blocks per layer
#define MAXBIN 256       // upper bound on bins (N <= 131072)
#define CSTRIDE 16       // bincur stride in ints (one counter per 64B line)

typedef __bf16 bf16x8 __attribute__((ext_vector_type(8)));
typedef unsigned short ushort8 __attribute__((ext_vector_type(8)));
typedef float f32x4 __attribute__((ext_vector_type(4)));

// fp32 -> bf16 bits with round-to-nearest-even (inputs finite).
static __device__ __forceinline__ unsigned short f2bf(float f) {
    unsigned int u = __float_as_uint(f);
    u += 0x7fffu + ((u >> 16) & 1u);
    return (unsigned short)(u >> 16);
}
// packed uint (2 bf16) -> 2 floats
static __device__ __forceinline__ void bf2x(unsigned int u, float& lo, float& hi) {
    lo = __uint_as_float(u << 16);
    hi = __uint_as_float(u & 0xffff0000u);
}

#define WPITCH 136   // ushorts per WT row: 128 + 8 pad (16B-aligned rows)
#define CPITCH 136   // epilogue C-staging pitch (272B rows: 16B aligned, <=2-way banks)
#define LDSN (F * WPITCH)   // 17408 ushorts = 34816 B (== 4 waves * 32*136 for epilogue)

// GEMM body: Y_bf16[n,128] = act(X[n,128]) @ W[128,128], bf16 MFMA, fp32 acc.
// Epilogue: per-wave LDS transpose (reusing WT) -> ushort8 coalesced stores.
template <int RELU, int INBF>
static __device__ void gemm_body(const void* __restrict__ Xv,
                                 const float* __restrict__ W,
                                 unsigned short* __restrict__ Y,
                                 int n, int blk, unsigned short* __restrict__ WT) {
    for (int idx = threadIdx.x; idx < F * F; idx += 256) {
        const int k = idx >> 7, c = idx & 127;
        WT[c * WPITCH + k] = f2bf(W[idx]);
    }
    __syncthreads();

    const int lane = threadIdx.x & 63;
    const int wv = threadIdx.x >> 6;
    const int m15 = lane & 15;
    const int quad = lane >> 4;
    const int rowBase = blk * 128 + wv * 32;

    f32x4 acc[2][8];
#pragma unroll
    for (int rt = 0; rt < 2; ++rt)
#pragma unroll
        for (int ct = 0; ct < 8; ++ct) acc[rt][ct] = (f32x4){0.f, 0.f, 0.f, 0.f};

    int rA[2];
    rA[0] = min(rowBase + m15, n - 1);        // clamped; stores masked below
    rA[1] = min(rowBase + 16 + m15, n - 1);

#pragma unroll
    for (int ks = 0; ks < 4; ++ks) {
        const int k0 = ks * 32 + quad * 8;    // this lane's 8-wide k window
        bf16x8 a[2];
#pragma unroll
        for (int rt = 0; rt < 2; ++rt) {
            if (INBF) {
                const unsigned short* Xb = (const unsigned short*)Xv;
                ushort8 u = *(const ushort8*)(Xb + (size_t)rA[rt] * F + k0);
                if (RELU) {
#pragma unroll
                    for (int j = 0; j < 8; ++j) u[j] = (u[j] & 0x8000u) ? 0 : u[j];
                }
                a[rt] = __builtin_bit_cast(bf16x8, u);
            } else {
                const float* Xf = (const float*)Xv;
                const float* p = Xf + (size_t)rA[rt] * F + k0;
                float4 lo = *(const float4*)p;
                float4 hi = *(const float4*)(p + 4);
                if (RELU) {
                    lo.x = fmaxf(lo.x, 0.f); lo.y = fmaxf(lo.y, 0.f);
                    lo.z = fmaxf(lo.z, 0.f); lo.w = fmaxf(lo.w, 0.f);
                    hi.x = fmaxf(hi.x, 0.f); hi.y = fmaxf(hi.y, 0.f);
                    hi.z = fmaxf(hi.z, 0.f); hi.w = fmaxf(hi.w, 0.f);
                }
                ushort8 u;
                u[0] = f2bf(lo.x); u[1] = f2bf(lo.y); u[2] = f2bf(lo.z); u[3] = f2bf(lo.w);
                u[4] = f2bf(hi.x); u[5] = f2bf(hi.y); u[6] = f2bf(hi.z); u[7] = f2bf(hi.w);
                a[rt] = __builtin_bit_cast(bf16x8, u);
            }
        }
#pragma unroll
        for (int ct = 0; ct < 8; ++ct) {
            const int nn = ct * 16 + m15;
            const bf16x8 b = *(const bf16x8*)(WT + nn * WPITCH + k0);  // ds_read_b128
            acc[0][ct] = __builtin_amdgcn_mfma_f32_16x16x32_bf16(a[0], b, acc[0][ct], 0, 0, 0);
            acc[1][ct] = __builtin_amdgcn_mfma_f32_16x16x32_bf16(a[1], b, acc[1][ct], 0, 0, 0);
        }
    }

    // ---- epilogue: reuse WT as per-wave C staging (32 rows x CPITCH ushorts) ----
    __syncthreads();                       // all waves done reading WT
    unsigned short* CW = WT + wv * 32 * CPITCH;
    // write: C/D layout col=lane&15, row=quad*4+reg (per 16x16 tile)
#pragma unroll
    for (int rt = 0; rt < 2; ++rt)
#pragma unroll
        for (int reg = 0; reg < 4; ++reg) {
            const int row = rt * 16 + quad * 4 + reg;
#pragma unroll
            for (int ct = 0; ct < 8; ++ct)
                CW[row * CPITCH + ct * 16 + m15] = f2bf(acc[rt][ct][reg]);
        }
    __syncthreads();                       // wave-internal ordering (cheap, uniform)
    // read back row-major, 16B per lane, coalesced 256B-row global stores
#pragma unroll
    for (int j = 0; j < 8; ++j) {
        const int row = j * 4 + quad;
        const int grow = rowBase + row;
        if (grow < n) {
            ushort8 o = *(const ushort8*)(CW + row * CPITCH + m15 * 8);
            *(ushort8*)(Y + (size_t)grow * F + m15 * 8) = o;
        }
    }
}

// Scatter body: per-block LDS histogram, one bulk atomicAdd per (block,bin) on
// line-strided cursors (pre-zeroed by memset), append into reserved runs.
static __device__ void scatter_body(
    const int* __restrict__ ei, const float* __restrict__ ew,
    int* __restrict__ bc, uint2* __restrict__ Ep,
    int E, int nbin, int cap, int blk, int* __restrict__ sh) {
    int* h = sh; int* base = sh + MAXBIN; int* cur = sh + 2 * MAXBIN;
    for (int i = threadIdx.x; i < nbin; i += 256) h[i] = 0;
    __syncthreads();
    const int chunk = (E + NBLKA - 1) / NBLKA;
    const int lo = blk * chunk;
    const int hi = min(lo + chunk, E);
    for (int e = lo + threadIdx.x; e < hi; e += 256)
        atomicAdd(&h[((unsigned)ei[E + e]) >> BSH], 1);
    __syncthreads();
    for (int i = threadIdx.x; i < nbin; i += 256) {
        cur[i] = 0;
        base[i] = h[i] ? atomicAdd(&bc[i * CSTRIDE], h[i]) : 0;
    }
    __syncthreads();
    for (int e = lo + threadIdx.x; e < hi; e += 256) {
        const unsigned int dst = (unsigned int)ei[E + e];
        const unsigned int src = (unsigned int)ei[e];
        const int b = (int)(dst >> BSH);
        const int slot = base[b] + atomicAdd(&cur[b], 1);
        if (slot < cap)   // statistically impossible overflow; memory-safety guard
            Ep[(size_t)b * cap + slot] =
                make_uint2(src | ((dst & (BSZ - 1)) << 20), (unsigned)__float_as_int(ew[e]));
    }
}

// K1: scatter blocks (both layers) first, then gemm1 blocks — independent work
// co-scheduled on the same CUs (scatter is VALU-idle, gemm is MFMA-heavy).
__global__ __launch_bounds__(256) void fused_gemm1_scatter(
    const float* __restrict__ x, const float* __restrict__ W1,
    unsigned short* __restrict__ Abf, int n,
    const int* __restrict__ ei1, const float* __restrict__ ew1,
    const int* __restrict__ ei2, const float* __restrict__ ew2,
    int* __restrict__ bc1, int* __restrict__ bc2,
    uint2* __restrict__ Ep1, uint2* __restrict__ Ep2,
    int E1, int E2, int nbin, int cap) {
    __shared__ __align__(16) unsigned short SH[LDSN];
    if (blockIdx.x < 2 * NBLKA) {
        const int layer2 = blockIdx.x >= NBLKA;
        scatter_body(layer2 ? ei2 : ei1, layer2 ? ew2 : ew1,
                     layer2 ? bc2 : bc1, layer2 ? Ep2 : Ep1,
                     layer2 ? E2 : E1, nbin, cap,
                     layer2 ? blockIdx.x - NBLKA : blockIdx.x, (int*)SH);
    } else {
        gemm_body<0, 0>(x, W1, Abf, n, blockIdx.x - 2 * NBLKA, SH);
    }
}

// K4: standalone gemm2 (relu(bf16 in) @ W2)
__global__ __launch_bounds__(256) void gemm128_mfma_l2(const unsigned short* __restrict__ X,
                                                       const float* __restrict__ W,
                                                       unsigned short* __restrict__ Y,
                                                       int n) {
    __shared__ __align__(16) unsigned short WT[LDSN];
    gemm_body<1, 1>(X, W, Y, n, blockIdx.x, WT);
}

// One block per (layer, bin): LDS hist/scan/rank over 512 local dsts; scatter
// within the bin's own fixed span; emit ebounds.
__global__ __launch_bounds__(512) void sort_both(
    const uint2* __restrict__ Ep1, const uint2* __restrict__ Ep2,
    const int* __restrict__ bc1, const int* __restrict__ bc2,
    uint2* __restrict__ Sg1, uint2* __restrict__ Sg2,
    int2* __restrict__ eb1, int2* __restrict__ eb2,
    int n, int nbin, int cap) {
    __shared__ int hist[BSZ], pref[BSZ], cur[BSZ];
    const int layer2 = blockIdx.x >= nbin;
    const int bin = layer2 ? blockIdx.x - nbin : blockIdx.x;
    const uint2* __restrict__ Ep = layer2 ? Ep2 : Ep1;
    const int* __restrict__ bc = layer2 ? bc2 : bc1;
    uint2* __restrict__ Sg = layer2 ? Sg2 : Sg1;
    int2* __restrict__ eb = layer2 ? eb2 : eb1;
    const int tid = threadIdx.x;
    const int base = bin * cap;
    const int cnt = min(bc[bin * CSTRIDE], cap);
    hist[tid] = 0;
    __syncthreads();
    for (int i = tid; i < cnt; i += 512)
        atomicAdd(&hist[Ep[(size_t)base + i].x >> 20], 1);
    __syncthreads();
    pref[tid] = hist[tid];
    __syncthreads();
    for (int off = 1; off < BSZ; off <<= 1) {
        int t = (tid >= off) ? pref[tid - off] : 0;
        __syncthreads();
        pref[tid] += t;
        __syncthreads();
    }
    {
        const int inc = pref[tid];
        const int ex = inc - hist[tid];
        cur[tid] = ex;
        const int v = (bin << BSH) + tid;
        if (v < n) eb[v] = make_int2(base + ex, base + inc);
    }
    __syncthreads();
    for (int i = tid; i < cnt; i += 512) {
        const uint2 e = Ep[(size_t)base + i];
        const int pos = atomicAdd(&cur[e.x >> 20], 1);
        Sg[(size_t)base + pos] = make_uint2(e.x & 0xFFFFFu, e.y);
    }
}

// OUT[v] = sum over incoming edges w_e * XW_bf16[src_e].
// 16 lanes per node, uint4 per lane; masked depth-4 windows.
// FUSE_U == 1: project fp32 row onto Wlin, write U[v] instead of the row.
template <int FUSE_U>
__global__ __launch_bounds__(256) void gather_agg(const unsigned short* __restrict__ XW,
                                                  const int2* __restrict__ ebounds,
                                                  const uint2* __restrict__ Sedge,
                                                  const float* __restrict__ Wlin,
                                                  unsigned short* __restrict__ OUT,
                                                  float4* __restrict__ U, int n) {
    __shared__ float WL[512];
    if (FUSE_U) {
        for (int i = threadIdx.x; i < 512; i += 256) WL[i] = Wlin[i];
        __syncthreads();
    }
    const int l = threadIdx.x & 15;              // 16 lanes per node
    const int v = blockIdx.x * 16 + (threadIdx.x >> 4);
    if (v >= n) return;
    float acc[8];
#pragma unroll
    for (int j = 0; j < 8; ++j) acc[j] = 0.f;
    const int2 be = ebounds[v];
    const int e2 = be.y;
    for (int p = be.x; p < e2; p += 4) {
        const int p1 = min(p + 1, e2 - 1);
        const int p2 = min(p + 2, e2 - 1);
        const int p3 = min(p + 3, e2 - 1);
        const uint2 s0 = Sedge[p],  s1 = Sedge[p1];
        const uint2 s2 = Sedge[p2], s3 = Sedge[p3];
        const uint4 x0 = ((const uint4*)(XW + (size_t)s0.x * F))[l];
        const uint4 x1 = ((const uint4*)(XW + (size_t)s1.x * F))[l];
        const uint4 x2 = ((const uint4*)(XW + (size_t)s2.x * F))[l];
        const uint4 x3 = ((const uint4*)(XW + (size_t)s3.x * F))[l];
        const float w0 = __int_as_float(s0.y);
        const float w1 = (p + 1 < e2) ? __int_as_float(s1.y) : 0.f;
        const float w2 = (p + 2 < e2) ? __int_as_float(s2.y) : 0.f;
        const float w3 = (p + 3 < e2) ? __int_as_float(s3.y) : 0.f;
        float a0, a1, a2, a3, a4, a5, a6, a7;
        bf2x(x0.x, a0, a1); bf2x(x0.y, a2, a3); bf2x(x0.z, a4, a5); bf2x(x0.w, a6, a7);
        acc[0] = fmaf(w0, a0, acc[0]); acc[1] = fmaf(w0, a1, acc[1]);
        acc[2] = fmaf(w0, a2, acc[2]); acc[3] = fmaf(w0, a3, acc[3]);
        acc[4] = fmaf(w0, a4, acc[4]); acc[5] = fmaf(w0, a5, acc[5]);
        acc[6] = fmaf(w0, a6, acc[6]); acc[7] = fmaf(w0, a7, acc[7]);
        bf2x(x1.x, a0, a1); bf2x(x1.y, a2, a3); bf2x(x1.z, a4, a5); bf2x(x1.w, a6, a7);
        acc[0] = fmaf(w1, a0, acc[0]); acc[1] = fmaf(w1, a1, acc[1]);
        acc[2] = fmaf(w1, a2, acc[2]); acc[3] = fmaf(w1, a3, acc[3]);
        acc[4] = fmaf(w1, a4, acc[4]); acc[5] = fmaf(w1, a5, acc[5]);
        acc[6] = fmaf(w1, a6, acc[6]); acc[7] = fmaf(w1, a7, acc[7]);
        bf2x(x2.x, a0, a1); bf2x(x2.y, a2, a3); bf2x(x2.z, a4, a5); bf2x(x2.w, a6, a7);
        acc[0] = fmaf(w2, a0, acc[0]); acc[1] = fmaf(w2, a1, acc[1]);
        acc[2] = fmaf(w2, a2, acc[2]); acc[3] = fmaf(w2, a3, acc[3]);
        acc[4] = fmaf(w2, a4, acc[4]); acc[5] = fmaf(w2, a5, acc[5]);
        acc[6] = fmaf(w2, a6, acc[6]); acc[7] = fmaf(w2, a7, acc[7]);
        bf2x(x3.x, a0, a1); bf2x(x3.y, a2, a3); bf2x(x3.z, a4, a5); bf2x(x3.w, a6, a7);
        acc[0] = fmaf(w3, a0, acc[0]); acc[1] = fmaf(w3, a1, acc[1]);
        acc[2] = fmaf(w3, a2, acc[2]); acc[3] = fmaf(w3, a3, acc[3]);
        acc[4] = fmaf(w3, a4, acc[4]); acc[5] = fmaf(w3, a5, acc[5]);
        acc[6] = fmaf(w3, a6, acc[6]); acc[7] = fmaf(w3, a7, acc[7]);
    }
    if (!FUSE_U) {
        ushort8 o;
#pragma unroll
        for (int j = 0; j < 8; ++j) o[j] = f2bf(acc[j]);
        *(ushort8*)(OUT + (size_t)v * F + (size_t)l * 8) = o;
    } else {
        const int k = l * 8;
        float s0 = 0.f, s1 = 0.f, s2 = 0.f, s3 = 0.f;
#pragma unroll
        for (int j = 0; j < 8; ++j) {
            s0 = fmaf(acc[j], WL[k + j],       s0);
            s1 = fmaf(acc[j], WL[128 + k + j], s1);
            s2 = fmaf(acc[j], WL[256 + k + j], s2);
            s3 = fmaf(acc[j], WL[384 + k + j], s3);
        }
#pragma unroll
        for (int off = 8; off > 0; off >>= 1) {
            s0 += __shfl_down(s0, off, 16);
            s1 += __shfl_down(s1, off, 16);
            s2 += __shfl_down(s2, off, 16);
            s3 += __shfl_down(s3, off, 16);
        }
        if (l == 0) U[v] = make_float4(s0, s1, s2, s3);
    }
}

// out[p,:] = (U[a].x + U[b].y, U[a].z + U[b].w); one thread per pair.
__global__ __launch_bounds__(256) void pair_combine(const float4* __restrict__ U,
                                                    const int* __restrict__ pos,
                                                    float* __restrict__ out, int P) {
    const int p = blockIdx.x * 256 + threadIdx.x;
    if (p >= P) return;
    const int a = pos[p];
    const int b = pos[P + p];
    const float4 ua = U[a];
    const float4 ub = U[b];
    *(float2*)(out + (size_t)p * 2) = make_float2(ua.x + ub.y, ua.z + ub.w);
}

extern "C" void kernel_launch(void* const* d_in, const int* in_sizes, int n_in,
                              void* d_out, int out_size, void* d_ws, size_t ws_size,
                              hipStream_t stream) {
    const float* x    = (const float*)d_in[0];
    const int*   ei1  = (const int*)  d_in[1];
    const int*   ei2  = (const int*)  d_in[2];
    const float* ew1  = (const float*)d_in[3];
    const float* ew2  = (const float*)d_in[4];
    const int*   pos  = (const int*)  d_in[5];
    const float* W1   = (const float*)d_in[6];
    const float* W2   = (const float*)d_in[7];
    const float* Wlin = (const float*)d_in[8];
    float* out = (float*)d_out;

    const int N  = in_sizes[0] / F;
    const int E1 = in_sizes[1] / 2;
    const int E2 = in_sizes[2] / 2;
    const int P  = in_sizes[5] / 2;
    const int Emax = E1 > E2 ? E1 : E2;
    const int NBIN = (N + BSZ - 1) >> BSH;          // 196 for N=100k (<= MAXBIN)
    const int cap  = Emax / NBIN + 512;             // ~avg + 8 sigma

    // workspace layout
    unsigned short* Abf = (unsigned short*)d_ws;    // N x 128 bf16 (GEMM out)
    unsigned short* Bbf = Abf + (size_t)N * F;      // N x 128 bf16 (gather-1 out)
    uintptr_t up  = (uintptr_t)(Bbf + (size_t)N * F);
    up = (up + 15) & ~(uintptr_t)15;
    float4* U     = (float4*)up;                    // N (node projections)
    int2*   eb1   = (int2*)(U + N);                 // N
    int2*   eb2   = eb1 + N;                        // N
    int*    bc1   = (int*)(eb2 + N);                // NBIN * CSTRIDE (line-strided)
    int*    bc2   = bc1 + NBIN * CSTRIDE;           // NBIN * CSTRIDE
    uintptr_t sp  = (uintptr_t)(bc2 + NBIN * CSTRIDE);
    sp = (sp + 15) & ~(uintptr_t)15;
    uint2* Ep1   = (uint2*)sp;                      // NBIN*cap
    uint2* Sg1   = Ep1 + (size_t)NBIN * cap;        // NBIN*cap
    uint2* Ep2   = Sg1 + (size_t)NBIN * cap;        // NBIN*cap
    uint2* Sg2   = Ep2 + (size_t)NBIN * cap;        // NBIN*cap

    const int gB = (N + 127) / 128;

    // 0) zero both layers' bin cursors (25 KB)
    hipMemsetAsync(bc1, 0, (size_t)2 * NBIN * CSTRIDE * sizeof(int), stream);
    // 1) fused: partition both edge lists (blocks 0..511) + Abf = x @ W1
    fused_gemm1_scatter<<<2 * NBLKA + gB, 256, 0, stream>>>(
        x, W1, Abf, N, ei1, ew1, ei2, ew2, bc1, bc2, Ep1, Ep2, E1, E2, NBIN, cap);
    // 2) dst-sort both layers' bins, emit ebounds
    sort_both<<<2 * NBIN, 512, 0, stream>>>(
        Ep1, Ep2, bc1, bc2, Sg1, Sg2, eb1, eb2, N, NBIN, cap);
    // 3) Bbf = segment_sum over edges1
    gather_agg<0><<<(N + 15) / 16, 256, 0, stream>>>(Abf, eb1, Sg1, Wlin, Bbf, U, N);
    // 4) Abf = relu(Bbf) @ W2
    gemm128_mfma_l2<<<gB, 256, 0, stream>>>(Bbf, W2, Abf, N);
    // 5) U = Wlin-projected segment_sum over edges2
    gather_agg<1><<<(N + 15) / 16, 256, 0, stream>>>(Abf, eb2, Sg2, Wlin, Bbf, U, N);
    // 6) head
    pair_combine<<<(P + 255) / 256, 256, 0, stream>>>(U, pos, out, P);
}